// Round 14
// baseline (233.914 us; speedup 1.0000x reference)
//
#include <hip/hip_runtime.h>
#include <hip/hip_bf16.h>

typedef unsigned short u16;
typedef __attribute__((ext_vector_type(4))) float f32x4;
typedef __attribute__((ext_vector_type(8))) short short8;  // 8 bf16 raw bits
typedef __attribute__((ext_vector_type(4))) short bf16x4;

#define B_ 2
#define T_ 256
#define D_ 2048
#define H_ 32
#define HS_ 64
#define M_ 512          // B*T
#define ST_ 66
#define EPS_ 1e-5f
#define NC_ 16          // recurrence chunks
#define CL_ 16          // chunk length

__device__ __forceinline__ float bf2f(u16 u) {
    union { unsigned int i; float f; } c; c.i = ((unsigned int)u) << 16; return c.f;
}
__device__ __forceinline__ u16 f2bf(float f) {
    union { unsigned int i; float f; } c; c.f = f;
    unsigned int r = c.i + 0x7fffu + ((c.i >> 16) & 1u);   // round-to-nearest-even
    return (u16)(r >> 16);
}
__device__ __forceinline__ u16 f2bf_hw(float f) {
    __hip_bfloat16 b = __float2bfloat16(f);
    return *reinterpret_cast<u16*>(&b);
}

__device__ __forceinline__ void gld16(const u16* g, u16* l) {
    __builtin_amdgcn_global_load_lds((const __attribute__((address_space(1))) void*)g,
                                     (__attribute__((address_space(3))) void*)l, 16, 0, 0);
}

// ---------------- LayerNorm: x -> xln ----------------
__global__ __launch_bounds__(256) void ln_kernel(const float* __restrict__ x, const float* __restrict__ w,
                                                 const float* __restrict__ bias, float* __restrict__ xln)
{
    const int row = blockIdx.x;                 // 0..511
    const float* xr = x + (size_t)row * D_;
    float* orow = xln + (size_t)row * D_;
    const int t = threadIdx.x;
    f32x4 a0 = *(const f32x4*)(xr + t * 8);
    f32x4 a1 = *(const f32x4*)(xr + t * 8 + 4);
    float s = 0.f, q = 0.f;
#pragma unroll
    for (int i = 0; i < 4; i++) { s += a0[i] + a1[i]; q += a0[i]*a0[i] + a1[i]*a1[i]; }
#pragma unroll
    for (int off = 1; off < 64; off <<= 1) { s += __shfl_xor(s, off, 64); q += __shfl_xor(q, off, 64); }
    __shared__ float ls[4], lq[4];
    const int wid = t >> 6, lane = t & 63;
    if (lane == 0) { ls[wid] = s; lq[wid] = q; }
    __syncthreads();
    s = ls[0] + ls[1] + ls[2] + ls[3];
    q = lq[0] + lq[1] + lq[2] + lq[3];
    const float mu = s * (1.f / D_);
    const float var = q * (1.f / D_) - mu * mu;
    const float rs = rsqrtf(var + EPS_);
#pragma unroll
    for (int i = 0; i < 8; i++) {
        int d = t * 8 + i;
        float f = (i < 4) ? a0[i] : a1[i - 4];
        orow[d] = (f - mu) * rs * w[d] + bias[d];
    }
}

// ---------------- token shift: sx = prev - cur ; xxxb = bf16(xln + sx*maa_x) ----------------
__global__ __launch_bounds__(256) void shift_kernel(const float* __restrict__ xln, const float* __restrict__ state,
                                                    const float* __restrict__ maax, const int* __restrict__ ip,
                                                    float* __restrict__ sx, u16* __restrict__ xxxb)
{
    const size_t gid = (size_t)blockIdx.x * 256 + threadIdx.x;
    const size_t e = gid * 4;                   // 4 floats per thread
    const int row = (int)(e >> 11);
    const int d = (int)(e & 2047);
    const int tt = row & (T_ - 1);
    const int b = row >> 8;
    const float* prev;
    if (tt == 0) prev = state + ((size_t)b * ST_ + (size_t)(66 * ip[0] + 1)) * D_ + d;
    else         prev = xln + e - D_;
    f32x4 p = *(const f32x4*)prev;
    f32x4 c = *(const f32x4*)(xln + e);
    f32x4 mx = *(const f32x4*)(maax + d);
    f32x4 sv;
    bf16x4 xv;
#pragma unroll
    for (int i = 0; i < 4; i++) { sv[i] = p[i] - c[i]; xv[i] = (short)f2bf(c[i] + sv[i] * mx[i]); }
    *(f32x4*)(sx + e) = sv;
    *(bf16x4*)(xxxb + e) = xv;
}

// ---------------- transpose + bf16: out[n][k] = bf16(in[k][n]) ----------------
__global__ __launch_bounds__(256) void txp_kernel(const float* __restrict__ in, u16* __restrict__ out,
                                                  int K, int N)
{
    __shared__ float tile[32][33];
    const int k0 = blockIdx.x * 32, n0 = blockIdx.y * 32;
    const int c = threadIdx.x & 31, r8 = threadIdx.x >> 5;   // 0..7
#pragma unroll
    for (int i = 0; i < 4; i++) {
        int r = r8 + i * 8;
        tile[r][c] = in[(size_t)(k0 + r) * N + (n0 + c)];
    }
    __syncthreads();
#pragma unroll
    for (int i = 0; i < 4; i++) {
        int r = r8 + i * 8;
        out[(size_t)(n0 + r) * K + (k0 + c)] = f2bf(tile[c][r]);
    }
}

// ---------------- wave-dot GEMM: one wave per output, C[m,n] = act(A[m,:] . Wt[n,:]) ----------------
template<bool TANH>
__global__ __launch_bounds__(512) void wdot_kernel(const u16* __restrict__ A, const u16* __restrict__ Wt,
                                                   float* __restrict__ C, int N)
{
    const int gw = (int)((blockIdx.x * 512 + threadIdx.x) >> 6);  // global wave id
    const int lane = threadIdx.x & 63;
    const int m = gw / N, n = gw - m * N;
    const u16* a = A + (size_t)m * D_ + lane * 8;
    const u16* w = Wt + (size_t)n * D_ + lane * 8;
    float acc = 0.f;
#pragma unroll
    for (int i = 0; i < 4; i++) {
        short8 av = *(const short8*)(a + i * 512);
        short8 wv = *(const short8*)(w + i * 512);
#pragma unroll
        for (int j = 0; j < 8; j++)
            acc = fmaf(bf2f((u16)av[j]), bf2f((u16)wv[j]), acc);
    }
#pragma unroll
    for (int off = 1; off < 64; off <<= 1) acc += __shfl_xor(acc, off, 64);
    if (lane == 0) C[gw] = TANH ? tanhf(acc) : acc;
}

// ---------------- maa lora stage 2 + x5 build: all 5 f per thread, xln/sx read once ----------------
__global__ __launch_bounds__(256) void maa2_kernel(const float* __restrict__ t5, const float* __restrict__ w2,
                                                   const float* __restrict__ xln, const float* __restrict__ sxp,
                                                   const float* __restrict__ mk, const float* __restrict__ mw,
                                                   const float* __restrict__ mv, const float* __restrict__ mr,
                                                   const float* __restrict__ mg, u16* __restrict__ x5)
{
    const int gid = blockIdx.x * 256 + threadIdx.x;   // 2048*128
    const int d = gid & (D_ - 1);
    const int mg4 = gid >> 11;                        // 0..127
    const size_t m0 = (size_t)mg4 * 4;
    float xl[4], sv[4];
#pragma unroll
    for (int mm = 0; mm < 4; mm++) {
        const size_t e = (m0 + mm) * D_ + d;
        xl[mm] = xln[e];
        sv[mm] = sxp[e];
    }
    const float* t5b = t5 + m0 * 160;
#pragma unroll
    for (int f = 0; f < 5; f++) {
        const float* maa = (f == 0) ? mk : (f == 1) ? mw : (f == 2) ? mv : (f == 3) ? mr : mg;
        const float mf = maa[d];
        const float* w2f = w2 + (size_t)f * 32 * D_ + d;
        float a0 = 0, a1 = 0, a2 = 0, a3 = 0;
#pragma unroll 8
        for (int r = 0; r < 32; r++) {
            const float wv = w2f[(size_t)r * D_];
            a0 = fmaf(t5b[f * 32 + r], wv, a0);
            a1 = fmaf(t5b[160 + f * 32 + r], wv, a1);
            a2 = fmaf(t5b[320 + f * 32 + r], wv, a2);
            a3 = fmaf(t5b[480 + f * 32 + r], wv, a3);
        }
        const float accs[4] = {a0, a1, a2, a3};
#pragma unroll
        for (int mm = 0; mm < 4; mm++) {
            const size_t e = (m0 + mm) * D_ + d;
            x5[(size_t)f * M_ * D_ + e] = f2bf(xl[mm] + sv[mm] * (mf + accs[mm]));
        }
    }
}

// ---------------- decay lora stage 2: w = exp(-exp(time_decay + td @ dw2)) ----------------
__global__ __launch_bounds__(256) void decay2_kernel(const float* __restrict__ td, const float* __restrict__ dw2,
                                                     const float* __restrict__ tdec, float* __restrict__ wout)
{
    const int gid = blockIdx.x * 256 + threadIdx.x;   // 2048*128
    const int d = gid & (D_ - 1);
    const int mg4 = gid >> 11;                        // 0..127
    const float* wp = dw2 + d;
    const float* tb = td + (size_t)mg4 * 4 * 64;
    float a0 = 0, a1 = 0, a2 = 0, a3 = 0;
#pragma unroll 8
    for (int r = 0; r < 64; r++) {
        float wv = wp[(size_t)r * D_];
        a0 = fmaf(tb[r], wv, a0);
        a1 = fmaf(tb[64 + r], wv, a1);
        a2 = fmaf(tb[128 + r], wv, a2);
        a3 = fmaf(tb[192 + r], wv, a3);
    }
    const float base = tdec[d];
    const float accs[4] = {a0, a1, a2, a3};
#pragma unroll
    for (int mm = 0; mm < 4; mm++)
        wout[((size_t)mg4 * 4 + mm) * D_ + d] = expf(-expf(base + accs[mm]));
}

// ---------------- bf16 GEMM: 128x64 tile, BK=64, A via gld16+swizzle (32KB LDS), B reg-direct ----------------
// B fragments loaded straight from f32 weights into regs (MFMA B layout), converted in-reg.
// Counted vmcnt(12) keeps next tile's 12 VMEM ops (4 gld16 + 8 f32x4) in flight across barriers.
__device__ __forceinline__ void gemm2p_body(const u16* __restrict__ A, const float* __restrict__ Wf,
                                            float* __restrict__ C, int m0, int n0, int k0, int KC)
{
    __shared__ u16 As[2][128 * 64];   // 32 KB total
    const int tid = threadIdx.x;      // 0..255
    const int lane = tid & 63;
    const int wvd = tid >> 6;         // 0..3
    const int wm = (wvd >> 1) * 64;   // 0,64
    const int wn = (wvd & 1) * 32;    // 0,32

    f32x4 acc[4][2];
#pragma unroll
    for (int i = 0; i < 4; i++)
#pragma unroll
        for (int j = 0; j < 2; j++) { acc[i][j][0]=0.f; acc[i][j][1]=0.f; acc[i][j][2]=0.f; acc[i][j][3]=0.f; }

    // A staging: thread covers rows srow+32i (i=0..3), dest chunk schk; source chunk pre-swizzled
    const int srow = tid >> 3;                       // 0..31
    const int schk = tid & 7;                        // 0..7
    const u16* Ag = A + (size_t)(m0 + srow) * D_ + k0 + ((schk ^ (srow & 7)) << 3);
    const int ldst = tid * 8;                        // linear dest: row*64 + schk*8

    const int fr = lane & 15;
    const int gq = lane >> 4;                        // k-quarter 0..3

    // B fragment base: lane reads B[n0+wn+fr][k0 + gq*8 + ...]; ni adds 16 rows, kk adds 32 cols
    const float* Bg = Wf + (size_t)(n0 + wn + fr) * D_ + k0 + gq * 8;

    // named B f32 double sets (all indices compile-time in unrolled loops)
    f32x4 bc[8], bn[8];

#define LOADB_(dst, kt)                                                           \
    {                                                                             \
        _Pragma("unroll")                                                         \
        for (int ni = 0; ni < 2; ni++)                                            \
        _Pragma("unroll")                                                         \
        for (int kk = 0; kk < 2; kk++) {                                          \
            const float* p = Bg + (size_t)(ni * 16) * D_ + (kt) + kk * 32;        \
            dst[ni * 4 + kk * 2 + 0] = *(const f32x4*)p;                          \
            dst[ni * 4 + kk * 2 + 1] = *(const f32x4*)(p + 4);                    \
        }                                                                         \
    }
#define STAGEA_(bb, kt)                                                           \
    {                                                                             \
        _Pragma("unroll")                                                         \
        for (int i = 0; i < 4; i++)                                               \
            gld16(Ag + (size_t)(i * 32) * D_ + (kt), &As[bb][i * 2048 + ldst]);   \
    }
#define MFMA_(bb, BR)                                                             \
    {                                                                             \
        _Pragma("unroll")                                                         \
        for (int kk2 = 0; kk2 < 2; kk2++) {                                       \
            short8 av[4], bv[2];                                                  \
            _Pragma("unroll")                                                     \
            for (int mi = 0; mi < 4; mi++) {                                      \
                const int row = wm + mi * 16 + fr;                                \
                const int g = (gq + kk2 * 4) ^ (row & 7);                         \
                av[mi] = *(const short8*)&As[bb][row * 64 + g * 8];               \
            }                                                                     \
            _Pragma("unroll")                                                     \
            for (int ni = 0; ni < 2; ni++) {                                      \
                const f32x4 lo = BR[ni * 4 + kk2 * 2];                            \
                const f32x4 hi = BR[ni * 4 + kk2 * 2 + 1];                        \
                short8 t;                                                         \
                _Pragma("unroll")                                                 \
                for (int j = 0; j < 4; j++) {                                     \
                    t[j]     = (short)f2bf_hw(lo[j]);                             \
                    t[j + 4] = (short)f2bf_hw(hi[j]);                             \
                }                                                                 \
                bv[ni] = t;                                                       \
            }                                                                     \
            _Pragma("unroll")                                                     \
            for (int mi = 0; mi < 4; mi++)                                        \
            _Pragma("unroll")                                                     \
            for (int ni = 0; ni < 2; ni++)                                        \
                acc[mi][ni] = __builtin_amdgcn_mfma_f32_16x16x32_bf16(av[mi], bv[ni], acc[mi][ni], 0, 0, 0); \
        }                                                                         \
    }

    // prologue: tile 0 (4 gld16 + 8 B loads in flight)
    STAGEA_(0, 0);
    LOADB_(bc, 0);
    for (int kt = 0; ; kt += 128) {
        {   // phase A: compute tile kt from buf0/bc
            const bool m1 = kt + 64 < KC;
            if (m1) { STAGEA_(1, kt + 64); LOADB_(bn, kt + 64); }
            if (m1) asm volatile("s_waitcnt vmcnt(12)" ::: "memory");
            else    asm volatile("s_waitcnt vmcnt(0)" ::: "memory");
            __builtin_amdgcn_s_barrier();           // As[0] ready (every wave waited its own DMA)
            MFMA_(0, bc);
            __builtin_amdgcn_s_barrier();           // all reads of As[0] done
            if (!m1) break;
        }
        {   // phase B: compute tile kt+64 from buf1/bn
            const bool m2 = kt + 128 < KC;
            if (m2) { STAGEA_(0, kt + 128); LOADB_(bc, kt + 128); }
            if (m2) asm volatile("s_waitcnt vmcnt(12)" ::: "memory");
            else    asm volatile("s_waitcnt vmcnt(0)" ::: "memory");
            __builtin_amdgcn_s_barrier();
            MFMA_(1, bn);
            __builtin_amdgcn_s_barrier();
            if (!m2) break;
        }
    }
#undef LOADB_
#undef STAGEA_
#undef MFMA_
    // epilogue: C/D layout col=lane&15, row=(lane>>4)*4+reg
    const int cr = wm + gq * 4;
    const int cc = wn + fr;
#pragma unroll
    for (int mi = 0; mi < 4; mi++)
#pragma unroll
        for (int ni = 0; ni < 2; ni++)
#pragma unroll
            for (int j = 0; j < 4; j++)
                C[(size_t)(m0 + cr + mi * 16 + j) * D_ + (n0 + cc + ni * 16)] = acc[mi][ni][j];
}

// gemm4: z = s*2 + ks (split-K 2, KC=1024)
__global__ __launch_bounds__(256) void gemm4g_kernel(const u16* __restrict__ x5, const float* __restrict__ Wk,
                                                     const float* __restrict__ Wv, const float* __restrict__ Wr,
                                                     const float* __restrict__ Wg, float* __restrict__ kvK,
                                                     float* __restrict__ kvV, float* __restrict__ kvR,
                                                     float* __restrict__ kvG, float* __restrict__ pp4)
{
    const int s  = blockIdx.z >> 1;
    const int ks = blockIdx.z & 1;
    const u16* A = x5 + (size_t)(s == 0 ? 0 : s + 1) * M_ * D_;
    const float* W = (s == 0) ? Wk : (s == 1) ? Wv : (s == 2) ? Wr : Wg;
    float* C = (ks == 0) ? ((s == 0) ? kvK : (s == 1) ? kvV : (s == 2) ? kvR : kvG)
                         : pp4 + (size_t)s * M_ * D_;
    gemm2p_body(A, W, C, blockIdx.y * 128, blockIdx.x * 64, ks * 1024, 1024);
}

__global__ __launch_bounds__(256) void add4g_kernel(float* __restrict__ dk, float* __restrict__ dv,
                                                    float* __restrict__ dr, float* __restrict__ dg,
                                                    const float* __restrict__ pp4)
{
    const int s = blockIdx.y;
    float* dst = (s == 0) ? dk : (s == 1) ? dv : (s == 2) ? dr : dg;
    const size_t e = ((size_t)blockIdx.x * 256 + threadIdx.x) * 4;
    f32x4 d = *(const f32x4*)(dst + e);
    f32x4 a = *(const f32x4*)(pp4 + (size_t)s * M_ * D_ + e);
#pragma unroll
    for (int i = 0; i < 4; i++) d[i] += a[i];
    *(f32x4*)(dst + e) = d;
}

// gemm1: z = ks 0..3 (split-K 4, KC=512)
__global__ __launch_bounds__(256) void gemm1g_kernel(const u16* __restrict__ y, const float* __restrict__ wo,
                                                     float* __restrict__ out, float* __restrict__ pp1)
{
    const int ks = blockIdx.z;
    float* C = (ks == 0) ? out : pp1 + (size_t)(ks - 1) * M_ * D_;
    gemm2p_body(y, wo, C, blockIdx.y * 128, blockIdx.x * 64, ks * 512, 512);
}

__global__ __launch_bounds__(256) void add3_kernel(float* __restrict__ dst, const float* __restrict__ pp1)
{
    const size_t e = ((size_t)blockIdx.x * 256 + threadIdx.x) * 4;
    const size_t MD = (size_t)M_ * D_;
    f32x4 d = *(const f32x4*)(dst + e);
#pragma unroll
    for (int i = 0; i < 3; i++) {
        f32x4 a = *(const f32x4*)(pp1 + (size_t)i * MD + e);
#pragma unroll
        for (int j = 0; j < 4; j++) d[j] += a[j];
    }
    *(f32x4*)(dst + e) = d;
}

// ================ recurrence: chunked linear scan ================
__global__ __launch_bounds__(512) void rec1_kernel(const float* __restrict__ rB, const float* __restrict__ kB,
                                                   const float* __restrict__ wB, const float* __restrict__ vB,
                                                   const float* __restrict__ fa, float* __restrict__ rwkv,
                                                   float* __restrict__ CS, float* __restrict__ RP,
                                                   float* __restrict__ PC)
{
    const int bx = blockIdx.x;            // (b*32+h)*16 + c
    const int c  = bx & (NC_ - 1);
    const int bh = bx >> 4;
    const int h = bh & 31, b = bh >> 5;
    const int tid = threadIdx.x;
    const int wv = tid >> 6, lane = tid & 63;
    const int wg = wv >> 2;
    const int jb = lane >> 3, dsub = lane & 7;
    const int jbase = jb * 8;
    const int d0 = wg * 32 + (wv & 3) * 8 + dsub;

    __shared__ float stage[4][CL_][64];   // 16 KB
    __shared__ float p2[CL_][8][64];      // 32 KB
    __shared__ float p1[CL_][8];
    __shared__ float rpS[CL_ * 64];       // 4 KB

    float S[8], pv[8], faj[8];
#pragma unroll
    for (int q = 0; q < 8; q++) { S[q] = 0.f; pv[q] = 1.f; faj[q] = fa[h * 64 + jbase + q]; }

    const size_t base = ((size_t)b * T_ * H_ + h) * HS_;
    const int t0 = c * CL_;
    const int arr = wv & 3;
    const float* mysrc = (arr == 0) ? rB : (arr == 1) ? kB : (arr == 2) ? wB : vB;
    const int ts0 = wg * 8 + (lane >> 4);
    const int sch = (lane & 15) * 4;
    const bool p1w = (wv == 0 && dsub == 0);

#pragma unroll
    for (int p = 0; p < 2; p++) {
        f32x4 v = *(const f32x4*)(mysrc + base + (size_t)(t0 + ts0 + p * 4) * (H_ * HS_) + sch);
        *(f32x4*)&stage[arr][ts0 + p * 4][sch] = v;
    }
    __syncthreads();

    f32x4 r0 = *(const f32x4*)&stage[0][0][jbase];
    f32x4 r1 = *(const f32x4*)&stage[0][0][jbase + 4];
    f32x4 k0 = *(const f32x4*)&stage[1][0][jbase];
    f32x4 k1 = *(const f32x4*)&stage[1][0][jbase + 4];
    f32x4 w0 = *(const f32x4*)&stage[2][0][jbase];
    f32x4 w1 = *(const f32x4*)&stage[2][0][jbase + 4];
    float vd = stage[3][0][d0];
#pragma unroll
    for (int ts = 0; ts < CL_; ++ts) {
        f32x4 nr0 = r0, nr1 = r1, nk0 = k0, nk1 = k1, nw0 = w0, nw1 = w1;
        float nvd = vd;
        if (ts + 1 < CL_) {
            nr0 = *(const f32x4*)&stage[0][ts + 1][jbase];
            nr1 = *(const f32x4*)&stage[0][ts + 1][jbase + 4];
            nk0 = *(const f32x4*)&stage[1][ts + 1][jbase];
            nk1 = *(const f32x4*)&stage[1][ts + 1][jbase + 4];
            nw0 = *(const f32x4*)&stage[2][ts + 1][jbase];
            nw1 = *(const f32x4*)&stage[2][ts + 1][jbase + 4];
            nvd = stage[3][ts + 1][d0];
        }
        float s1 = 0.f, s2 = 0.f;
#pragma unroll
        for (int q = 0; q < 4; q++) {
            s1 = fmaf(r0[q] * faj[q],     k0[q], s1);
            s1 = fmaf(r1[q] * faj[q + 4], k1[q], s1);
            s2 = fmaf(r0[q], S[q],     s2);
            s2 = fmaf(r1[q], S[q + 4], s2);
        }
        p2[ts][jb][d0 ^ (jb << 3)] = s2;
        if (p1w) {
            p1[ts][jb] = s1;
#pragma unroll
            for (int q = 0; q < 4; q++) {
                rpS[ts * 64 + jbase + q]     = r0[q] * pv[q];
                rpS[ts * 64 + jbase + 4 + q] = r1[q] * pv[q + 4];
            }
        }
#pragma unroll
        for (int q = 0; q < 4; q++) {
            pv[q]     *= w0[q];
            pv[q + 4] *= w1[q];
            S[q]       = fmaf(w0[q], S[q],     k0[q] * vd);
            S[q + 4]   = fmaf(w1[q], S[q + 4], k1[q] * vd);
        }
        r0 = nr0; r1 = nr1; k0 = nk0; k1 = nk1; w0 = nw0; w1 = nw1; vd = nvd;
    }
    __syncthreads();   // p2/p1/rpS complete
#pragma unroll
    for (int p = 0; p < 2; p++) {
        const int ts = wv * 2 + p;
        f32x4 p1a = *(const f32x4*)&p1[ts][0];
        f32x4 p1b = *(const f32x4*)&p1[ts][4];
        float s1t = ((p1a[0] + p1a[1]) + (p1a[2] + p1a[3])) +
                    ((p1b[0] + p1b[1]) + (p1b[2] + p1b[3]));
        float s2t = 0.f;
#pragma unroll
        for (int j = 0; j < 8; j++) s2t += p2[ts][j][lane ^ (j << 3)];
        const float vvv = stage[3][ts][lane];
        rwkv[base + (size_t)(t0 + ts) * (H_ * HS_) + lane] = fmaf(vvv, s1t, s2t);
    }
    RP[(size_t)bx * (CL_ * 64) + tid]       = rpS[tid];
    RP[(size_t)bx * (CL_ * 64) + 512 + tid] = rpS[512 + tid];
#pragma unroll
    for (int q = 0; q < 8; q++)
        CS[(size_t)bx * 4096 + (size_t)(jbase + q) * 64 + d0] = S[q];
    if (p1w) {
#pragma unroll
        for (int q = 0; q < 8; q++)
            PC[(size_t)bx * 64 + jbase + q] = pv[q];
    }
}

// rec2: sequential over chunks: Sstart_{c+1} = CS_c + PC_c * Sstart_c; CS[c] <- Sstart_c
__global__ __launch_bounds__(512) void rec2_kernel(const float* __restrict__ state, const int* __restrict__ ip,
                                                   float* __restrict__ CS, const float* __restrict__ PC)
{
    const int bh = blockIdx.x;            // b*32+h
    const int b = bh >> 5, h = bh & 31;
    const int tid = threadIdx.x;
    const int o = tid * 8;
    const int jrow = tid >> 3;
    const float* Sp = state + (size_t)b * ST_ * D_ + (size_t)(66 * ip[0] + 2) * D_ + (size_t)h * HS_ * HS_;
    f32x4 c0 = *(const f32x4*)(Sp + o);
    f32x4 c1 = *(const f32x4*)(Sp + o + 4);
    for (int c = 0; c < NC_; ++c) {
        float* cs = CS + ((size_t)(bh * NC_ + c)) * 4096 + o;
        f32x4 l0 = *(const f32x4*)cs;
        f32x4 l1 = *(const f32x4*)(cs + 4);
        const float pc = PC[(size_t)(bh * NC_ + c) * 64 + jrow];
        f32x4 n0, n1;
#pragma unroll
        for (int i = 0; i < 4; i++) { n0[i] = fmaf(pc, c0[i], l0[i]); n1[i] = fmaf(pc, c1[i], l1[i]); }
        *(f32x4*)cs = c0;
        *(f32x4*)(cs + 4) = c1;
        c0 = n0; c1 = n1;
    }
}

// rec3gn: val = rwkv_partial + rp.Sstart, then fused groupnorm + silu gate -> y (bf16)
__global__ __launch_bounds__(256) void rec3gn_kernel(const float* __restrict__ CS, const float* __restrict__ RP,
                                                     const float* __restrict__ rwkv, const float* __restrict__ gpre,
                                                     const float* __restrict__ lnxw, const float* __restrict__ lnxb,
                                                     u16* __restrict__ y)
{
    const int bx = blockIdx.x;            // (b*32+h)*16 + c
    const int c  = bx & (NC_ - 1);
    const int bh = bx >> 4;
    const int h = bh & 31, b = bh >> 5;
    const int tid = threadIdx.x;
    __shared__ float Ss[4096];            // [j][d]
    __shared__ float rp[CL_ * 64];        // [tl][j]
#pragma unroll
    for (int i = 0; i < 4; i++)
        *(f32x4*)&Ss[tid * 4 + i * 1024] = *(const f32x4*)(CS + (size_t)bx * 4096 + tid * 4 + i * 1024);
    *(f32x4*)&rp[tid * 4] = *(const f32x4*)(RP + (size_t)bx * (CL_ * 64) + tid * 4);
    __syncthreads();
    const int tl = tid >> 4;              // 0..15 (local t)
    const int d4 = (tid & 15) * 4;
    f32x4 acc; acc[0] = acc[1] = acc[2] = acc[3] = 0.f;
    const float* rpr = &rp[tl * 64];
#pragma unroll 16
    for (int j = 0; j < 64; ++j) {
        const float rv = rpr[j];
        const f32x4 sv = *(const f32x4*)&Ss[j * 64 + d4];
#pragma unroll
        for (int i = 0; i < 4; i++) acc[i] = fmaf(rv, sv[i], acc[i]);
    }
    const size_t base = ((size_t)b * T_ * H_ + h) * HS_;
    const size_t eb = base + (size_t)(c * CL_ + tl) * (H_ * HS_);
    const f32x4 cur = *(const f32x4*)(rwkv + eb + d4);
    f32x4 val;
#pragma unroll
    for (int i = 0; i < 4; i++) val[i] = cur[i] + acc[i];
    float s = 0.f, q = 0.f;
#pragma unroll
    for (int i = 0; i < 4; i++) { s += val[i]; q += val[i] * val[i]; }
#pragma unroll
    for (int off = 1; off < 16; off <<= 1) { s += __shfl_xor(s, off, 64); q += __shfl_xor(q, off, 64); }
    const float mu = s * (1.f / 64.f);
    const float var = q * (1.f / 64.f) - mu * mu;
    const float rs = rsqrtf(var + EPS_);
    bf16x4 yv;
#pragma unroll
    for (int i = 0; i < 4; i++) {
        const int hj = h * 64 + d4 + i;
        const float nrm = (val[i] - mu) * rs * lnxw[hj] + lnxb[hj];
        const float gp = gpre[eb + d4 + i];
        const float gv = gp / (1.f + expf(-gp));
        yv[i] = (short)f2bf(nrm * gv);
    }
    *(bf16x4*)(y + eb + d4) = yv;
}

extern "C" void kernel_launch(void* const* d_in, const int* in_sizes, int n_in,
                              void* d_out, int out_size, void* d_ws, size_t ws_size,
                              hipStream_t stream)
{
    const float* x     = (const float*)d_in[0];
    const float* state = (const float*)d_in[1];
    const float* ln1w  = (const float*)d_in[2];
    const float* ln1b  = (const float*)d_in[3];
    const float* maax  = (const float*)d_in[4];
    const float* w1    = (const float*)d_in[5];
    const float* w2    = (const float*)d_in[6];
    const float* maak  = (const float*)d_in[7];
    const float* maaw  = (const float*)d_in[8];
    const float* maav  = (const float*)d_in[9];
    const float* maar  = (const float*)d_in[10];
    const float* maag  = (const float*)d_in[11];
    const float* tdec  = (const float*)d_in[12];
    const float* dw1   = (const float*)d_in[13];
    const float* dw2   = (const float*)d_in[14];
    const float* fa    = (const float*)d_in[15];
    const float* wrec  = (const float*)d_in[16];
    const float* wkey  = (const float*)d_in[17];
    const float* wval  = (const float*)d_in[18];
    const float* wout  = (const float*)d_in[19];
    const float* wgate = (const float*)d_in[20];
    const float* lnxw  = (const float*)d_in[21];
    const float* lnxb  = (const float*)d_in[22];
    const int*   ip    = (const int*)d_in[23];

    char* ws = (char*)d_ws;
    const size_t MD = (size_t)M_ * D_;
    // lifetime-packed layout (78 MB budget)
    float* pp4  = (float*)(ws);                          // [0,16) during gemm4g
    float* CS   = (float*)(ws);                          // [0,16) rec phase
    float* RP   = (float*)(ws + ((size_t)16 << 20));     // [16,20)
    float* PC   = (float*)(ws + ((size_t)20 << 20));     // [20,20.25)
    float* pp1  = (float*)(ws);                          // [0,12) during gemm1g (CS/RP dead)
    float* xln  = (float*)(ws + ((size_t)40 << 20));     // [40,44)  dead after maa2
    float* sx   = (float*)(ws + ((size_t)44 << 20));     // [44,48)  dead after maa2
    u16*   xxxb = (u16*)  (ws + ((size_t)48 << 20));     // [48,50)  dead after wdot-maa1
    u16*   w1t  = (u16*)  (ws + ((size_t)50 << 20));     // [50,51)  dead after wdot-maa1
    u16*   dw1t = (u16*)  (ws + ((size_t)51 << 20));     // [51,52)  dead after wdot-decay1
    float* t5   = (float*)(ws + ((size_t)52 << 20));     // [52,53)  dead after maa2
    float* td   = (float*)(ws + ((size_t)53 << 20));     // [53,54)  dead after decay2
    u16*   x5   = (u16*)  (ws + ((size_t)54 << 20));     // [54,64)  dead after gemm4g
    float* wdec = (float*)(ws + ((size_t)64 << 20));     // [64,68)  dead after rec1
    float* kvK  = (float*)(ws + ((size_t)40 << 20));     // aliases xln  (dead)
    float* kvV  = (float*)(ws + ((size_t)44 << 20));     // aliases sx   (dead)
    float* kvR  = (float*)(ws + ((size_t)48 << 20));     // aliases xxxb/w1t/dw1t (dead)
    float* kvG  = (float*)(ws + ((size_t)68 << 20));     // [68,72)
    float* rwkv = (float*)(ws + ((size_t)72 << 20));     // [72,76)
    u16*   y    = (u16*)  (ws + ((size_t)76 << 20));     // [76,78)
    float* out  = (float*)d_out;

    hipLaunchKernelGGL(ln_kernel,     dim3(512),      dim3(256), 0, stream, x, ln1w, ln1b, xln);
    hipLaunchKernelGGL(shift_kernel,  dim3(1024),     dim3(256), 0, stream, xln, state, maax, ip, sx, xxxb);
    hipLaunchKernelGGL(txp_kernel,    dim3(64, 5),    dim3(256), 0, stream, w1, w1t, D_, 160);
    hipLaunchKernelGGL(txp_kernel,    dim3(64, 2),    dim3(256), 0, stream, dw1, dw1t, D_, 64);
    hipLaunchKernelGGL((wdot_kernel<true>), dim3(10240), dim3(512), 0, stream, xxxb, w1t, t5, 160);
    hipLaunchKernelGGL(maa2_kernel,   dim3(1024),     dim3(256), 0, stream, t5, w2, xln, sx, maak, maaw, maav, maar, maag, x5);
    hipLaunchKernelGGL((wdot_kernel<true>), dim3(4096), dim3(512), 0, stream, x5 + MD, dw1t, td, 64);
    hipLaunchKernelGGL(decay2_kernel, dim3(1024),     dim3(256), 0, stream, td, dw2, tdec, wdec);
    hipLaunchKernelGGL(gemm4g_kernel, dim3(32, 4, 8), dim3(256), 0, stream, x5, wkey, wval, wrec, wgate, kvK, kvV, kvR, kvG, pp4);
    hipLaunchKernelGGL(add4g_kernel,  dim3(1024, 4),  dim3(256), 0, stream, kvK, kvV, kvR, kvG, pp4);
    hipLaunchKernelGGL(rec1_kernel,   dim3(B_ * H_ * NC_), dim3(512), 0, stream, kvR, kvK, wdec, kvV, fa, rwkv, CS, RP, PC);
    hipLaunchKernelGGL(rec2_kernel,   dim3(B_ * H_),  dim3(512), 0, stream, state, ip, CS, PC);
    hipLaunchKernelGGL(rec3gn_kernel, dim3(B_ * H_ * NC_), dim3(256), 0, stream, CS, RP, rwkv, kvG, lnxw, lnxb, y);
    hipLaunchKernelGGL(gemm1g_kernel, dim3(32, 4, 4), dim3(256), 0, stream, y, wout, out, pp1);
    hipLaunchKernelGGL(add3_kernel,   dim3(1024),     dim3(256), 0, stream, out, pp1);

    (void)in_sizes; (void)n_in; (void)out_size; (void)ws_size;
}

// Round 15
// 174.934 us; speedup vs baseline: 1.3372x; 1.3372x over previous
//
#include <hip/hip_runtime.h>
#include <hip/hip_bf16.h>

typedef unsigned short u16;
typedef __attribute__((ext_vector_type(4))) float f32x4;
typedef __attribute__((ext_vector_type(8))) short short8;  // 8 bf16 raw bits
typedef __attribute__((ext_vector_type(4))) short bf16x4;

#define B_ 2
#define T_ 256
#define D_ 2048
#define H_ 32
#define HS_ 64
#define M_ 512          // B*T
#define ST_ 66
#define EPS_ 1e-5f
#define NC_ 16          // recurrence chunks
#define CL_ 16          // chunk length

__device__ __forceinline__ float bf2f(u16 u) {
    union { unsigned int i; float f; } c; c.i = ((unsigned int)u) << 16; return c.f;
}
__device__ __forceinline__ u16 f2bf(float f) {
    union { unsigned int i; float f; } c; c.f = f;
    unsigned int r = c.i + 0x7fffu + ((c.i >> 16) & 1u);   // round-to-nearest-even
    return (u16)(r >> 16);
}
__device__ __forceinline__ u16 f2bf_hw(float f) {
    __hip_bfloat16 b = __float2bfloat16(f);
    return *reinterpret_cast<u16*>(&b);
}

__device__ __forceinline__ void gld16(const u16* g, u16* l) {
    __builtin_amdgcn_global_load_lds((const __attribute__((address_space(1))) void*)g,
                                     (__attribute__((address_space(3))) void*)l, 16, 0, 0);
}

// ---------------- LayerNorm: x -> xln ----------------
__global__ __launch_bounds__(256) void ln_kernel(const float* __restrict__ x, const float* __restrict__ w,
                                                 const float* __restrict__ bias, float* __restrict__ xln)
{
    const int row = blockIdx.x;                 // 0..511
    const float* xr = x + (size_t)row * D_;
    float* orow = xln + (size_t)row * D_;
    const int t = threadIdx.x;
    f32x4 a0 = *(const f32x4*)(xr + t * 8);
    f32x4 a1 = *(const f32x4*)(xr + t * 8 + 4);
    float s = 0.f, q = 0.f;
#pragma unroll
    for (int i = 0; i < 4; i++) { s += a0[i] + a1[i]; q += a0[i]*a0[i] + a1[i]*a1[i]; }
#pragma unroll
    for (int off = 1; off < 64; off <<= 1) { s += __shfl_xor(s, off, 64); q += __shfl_xor(q, off, 64); }
    __shared__ float ls[4], lq[4];
    const int wid = t >> 6, lane = t & 63;
    if (lane == 0) { ls[wid] = s; lq[wid] = q; }
    __syncthreads();
    s = ls[0] + ls[1] + ls[2] + ls[3];
    q = lq[0] + lq[1] + lq[2] + lq[3];
    const float mu = s * (1.f / D_);
    const float var = q * (1.f / D_) - mu * mu;
    const float rs = rsqrtf(var + EPS_);
#pragma unroll
    for (int i = 0; i < 8; i++) {
        int d = t * 8 + i;
        float f = (i < 4) ? a0[i] : a1[i - 4];
        orow[d] = (f - mu) * rs * w[d] + bias[d];
    }
}

// ---------------- token shift: sx = prev - cur ; xxxb = bf16(xln + sx*maa_x) ----------------
__global__ __launch_bounds__(256) void shift_kernel(const float* __restrict__ xln, const float* __restrict__ state,
                                                    const float* __restrict__ maax, const int* __restrict__ ip,
                                                    float* __restrict__ sx, u16* __restrict__ xxxb)
{
    const size_t gid = (size_t)blockIdx.x * 256 + threadIdx.x;
    const size_t e = gid * 4;                   // 4 floats per thread
    const int row = (int)(e >> 11);
    const int d = (int)(e & 2047);
    const int tt = row & (T_ - 1);
    const int b = row >> 8;
    const float* prev;
    if (tt == 0) prev = state + ((size_t)b * ST_ + (size_t)(66 * ip[0] + 1)) * D_ + d;
    else         prev = xln + e - D_;
    f32x4 p = *(const f32x4*)prev;
    f32x4 c = *(const f32x4*)(xln + e);
    f32x4 mx = *(const f32x4*)(maax + d);
    f32x4 sv;
    bf16x4 xv;
#pragma unroll
    for (int i = 0; i < 4; i++) { sv[i] = p[i] - c[i]; xv[i] = (short)f2bf(c[i] + sv[i] * mx[i]); }
    *(f32x4*)(sx + e) = sv;
    *(bf16x4*)(xxxb + e) = xv;
}

// ---------------- transpose + bf16: out[n][k] = bf16(in[k][n]) ----------------
__global__ __launch_bounds__(256) void txp_kernel(const float* __restrict__ in, u16* __restrict__ out,
                                                  int K, int N)
{
    __shared__ float tile[32][33];
    const int k0 = blockIdx.x * 32, n0 = blockIdx.y * 32;
    const int c = threadIdx.x & 31, r8 = threadIdx.x >> 5;   // 0..7
#pragma unroll
    for (int i = 0; i < 4; i++) {
        int r = r8 + i * 8;
        tile[r][c] = in[(size_t)(k0 + r) * N + (n0 + c)];
    }
    __syncthreads();
#pragma unroll
    for (int i = 0; i < 4; i++) {
        int r = r8 + i * 8;
        out[(size_t)(n0 + r) * K + (k0 + c)] = f2bf(tile[c][r]);
    }
}

// ---------------- wave-dot GEMM: one wave per output, C[m,n] = act(A[m,:] . Wt[n,:]) ----------------
template<bool TANH>
__global__ __launch_bounds__(512) void wdot_kernel(const u16* __restrict__ A, const u16* __restrict__ Wt,
                                                   float* __restrict__ C, int N)
{
    const int gw = (int)((blockIdx.x * 512 + threadIdx.x) >> 6);  // global wave id
    const int lane = threadIdx.x & 63;
    const int m = gw / N, n = gw - m * N;
    const u16* a = A + (size_t)m * D_ + lane * 8;
    const u16* w = Wt + (size_t)n * D_ + lane * 8;
    float acc = 0.f;
#pragma unroll
    for (int i = 0; i < 4; i++) {
        short8 av = *(const short8*)(a + i * 512);
        short8 wv = *(const short8*)(w + i * 512);
#pragma unroll
        for (int j = 0; j < 8; j++)
            acc = fmaf(bf2f((u16)av[j]), bf2f((u16)wv[j]), acc);
    }
#pragma unroll
    for (int off = 1; off < 64; off <<= 1) acc += __shfl_xor(acc, off, 64);
    if (lane == 0) C[gw] = TANH ? tanhf(acc) : acc;
}

// ---------------- maa lora stage 2 + x5 build: all 5 f per thread, xln/sx read once ----------------
__global__ __launch_bounds__(256) void maa2_kernel(const float* __restrict__ t5, const float* __restrict__ w2,
                                                   const float* __restrict__ xln, const float* __restrict__ sxp,
                                                   const float* __restrict__ mk, const float* __restrict__ mw,
                                                   const float* __restrict__ mv, const float* __restrict__ mr,
                                                   const float* __restrict__ mg, u16* __restrict__ x5)
{
    const int gid = blockIdx.x * 256 + threadIdx.x;   // 2048*128
    const int d = gid & (D_ - 1);
    const int mg4 = gid >> 11;                        // 0..127
    const size_t m0 = (size_t)mg4 * 4;
    float xl[4], sv[4];
#pragma unroll
    for (int mm = 0; mm < 4; mm++) {
        const size_t e = (m0 + mm) * D_ + d;
        xl[mm] = xln[e];
        sv[mm] = sxp[e];
    }
    const float* t5b = t5 + m0 * 160;
#pragma unroll
    for (int f = 0; f < 5; f++) {
        const float* maa = (f == 0) ? mk : (f == 1) ? mw : (f == 2) ? mv : (f == 3) ? mr : mg;
        const float mf = maa[d];
        const float* w2f = w2 + (size_t)f * 32 * D_ + d;
        float a0 = 0, a1 = 0, a2 = 0, a3 = 0;
#pragma unroll 8
        for (int r = 0; r < 32; r++) {
            const float wv = w2f[(size_t)r * D_];
            a0 = fmaf(t5b[f * 32 + r], wv, a0);
            a1 = fmaf(t5b[160 + f * 32 + r], wv, a1);
            a2 = fmaf(t5b[320 + f * 32 + r], wv, a2);
            a3 = fmaf(t5b[480 + f * 32 + r], wv, a3);
        }
        const float accs[4] = {a0, a1, a2, a3};
#pragma unroll
        for (int mm = 0; mm < 4; mm++) {
            const size_t e = (m0 + mm) * D_ + d;
            x5[(size_t)f * M_ * D_ + e] = f2bf(xl[mm] + sv[mm] * (mf + accs[mm]));
        }
    }
}

// ---------------- decay lora stage 2: w = exp(-exp(time_decay + td @ dw2)) ----------------
__global__ __launch_bounds__(256) void decay2_kernel(const float* __restrict__ td, const float* __restrict__ dw2,
                                                     const float* __restrict__ tdec, float* __restrict__ wout)
{
    const int gid = blockIdx.x * 256 + threadIdx.x;   // 2048*128
    const int d = gid & (D_ - 1);
    const int mg4 = gid >> 11;                        // 0..127
    const float* wp = dw2 + d;
    const float* tb = td + (size_t)mg4 * 4 * 64;
    float a0 = 0, a1 = 0, a2 = 0, a3 = 0;
#pragma unroll 8
    for (int r = 0; r < 64; r++) {
        float wv = wp[(size_t)r * D_];
        a0 = fmaf(tb[r], wv, a0);
        a1 = fmaf(tb[64 + r], wv, a1);
        a2 = fmaf(tb[128 + r], wv, a2);
        a3 = fmaf(tb[192 + r], wv, a3);
    }
    const float base = tdec[d];
    const float accs[4] = {a0, a1, a2, a3};
#pragma unroll
    for (int mm = 0; mm < 4; mm++)
        wout[((size_t)mg4 * 4 + mm) * D_ + d] = expf(-expf(base + accs[mm]));
}

// ---------------- bf16 GEMM: 128x64 tile, BK=64, 512 threads (8 waves, 32x32 sub-tiles) ----------------
// A via global_load_lds + XOR swizzle (proven 0-conflict); B = f32 reg-staged -> bf16 -> LDS.
// Counted vmcnt(4): next tile's 4 VMEM ops/thread stay in flight across barriers.
__device__ __forceinline__ void gemm2p_body(const u16* __restrict__ A, const float* __restrict__ Wf,
                                            float* __restrict__ C, int m0, int n0, int k0, int KC)
{
    __shared__ u16 As[2][128 * 64];   // 32 KB
    __shared__ u16 Bs[2][64 * 64];    // 16 KB
    const int tid = threadIdx.x;      // 0..511
    const int lane = tid & 63;
    const int wvid = tid >> 6;        // 0..7
    const int wm = (wvid >> 1) * 32;  // 0,32,64,96
    const int wn = (wvid & 1) * 32;   // 0,32

    f32x4 acc[2][2];
#pragma unroll
    for (int i = 0; i < 2; i++)
#pragma unroll
        for (int j = 0; j < 2; j++) { acc[i][j][0]=0.f; acc[i][j][1]=0.f; acc[i][j][2]=0.f; acc[i][j][3]=0.f; }

    // A staging: rows srow, srow+64; dest chunk schk; source chunk pre-swizzled (rule #21)
    const int srow = tid >> 3;                       // 0..63
    const int schk = tid & 7;                        // 0..7
    const u16* Ag = A + (size_t)(m0 + srow) * D_ + k0 + ((schk ^ (srow & 7)) << 3);
    const int ldst = tid * 8;                        // = srow*64 + schk*8

    // B staging: row srow, f32 cols schk*8..+8 -> one short8 at swizzled chunk
    const float* Wg = Wf + (size_t)(n0 + srow) * D_ + k0 + schk * 8;
    const int bdst = srow * 64 + ((schk ^ (srow & 7)) << 3);

    // read-side: chunk g of row r lives at g ^ (r&7)
    const int fr = lane & 15;
    const int gq = lane >> 4;

    // named B-register double sets (rule #20)
    f32x4 xa0, xa1;   // buffer 0
    f32x4 xb0, xb1;   // buffer 1

#define LOADB_A(kt) { xa0 = *(const f32x4*)(Wg + (kt)); xa1 = *(const f32x4*)(Wg + (kt) + 4); }
#define LOADB_B(kt) { xb0 = *(const f32x4*)(Wg + (kt)); xb1 = *(const f32x4*)(Wg + (kt) + 4); }
#define STAGEA_(bb, kt)                                                           \
    {                                                                             \
        gld16(Ag + (kt), &As[bb][ldst]);                                          \
        gld16(Ag + (size_t)64 * D_ + (kt), &As[bb][4096 + ldst]);                 \
    }
#define WRITEB_(bb, r0, r1)                                                       \
    {                                                                             \
        short8 p0;                                                                \
        _Pragma("unroll")                                                         \
        for (int j = 0; j < 4; j++) {                                             \
            p0[j]     = (short)f2bf_hw(r0[j]);                                    \
            p0[j + 4] = (short)f2bf_hw(r1[j]);                                    \
        }                                                                         \
        *(short8*)&Bs[bb][bdst] = p0;                                             \
    }
#define MFMA_(bb)                                                                 \
    {                                                                             \
        _Pragma("unroll")                                                         \
        for (int kk = 0; kk < 2; kk++) {                                          \
            short8 av[2], bv[2];                                                  \
            _Pragma("unroll")                                                     \
            for (int mi = 0; mi < 2; mi++) {                                      \
                const int row = wm + mi * 16 + fr;                                \
                const int g = (gq + kk * 4) ^ (row & 7);                          \
                av[mi] = *(const short8*)&As[bb][row * 64 + g * 8];               \
            }                                                                     \
            _Pragma("unroll")                                                     \
            for (int ni = 0; ni < 2; ni++) {                                      \
                const int row = wn + ni * 16 + fr;                                \
                const int g = (gq + kk * 4) ^ (row & 7);                          \
                bv[ni] = *(const short8*)&Bs[bb][row * 64 + g * 8];               \
            }                                                                     \
            _Pragma("unroll")                                                     \
            for (int mi = 0; mi < 2; mi++)                                        \
            _Pragma("unroll")                                                     \
            for (int ni = 0; ni < 2; ni++)                                        \
                acc[mi][ni] = __builtin_amdgcn_mfma_f32_16x16x32_bf16(av[mi], bv[ni], acc[mi][ni], 0, 0, 0); \
        }                                                                         \
    }

    // prologue: tile 0 -> buf0 (4 VMEM ops/thread in flight)
    LOADB_A(0);
    STAGEA_(0, 0);
    for (int kt = 0; ; kt += 128) {
        {   // phase A: compute buf0 = tile kt
            const bool m1 = kt + 64 < KC;
            if (m1) { LOADB_B(kt + 64); STAGEA_(1, kt + 64); }
            if (m1) asm volatile("s_waitcnt vmcnt(4)" ::: "memory");
            else    asm volatile("s_waitcnt vmcnt(0)" ::: "memory");
            WRITEB_(0, xa0, xa1);
            asm volatile("s_waitcnt lgkmcnt(0)" ::: "memory");
            __builtin_amdgcn_s_barrier();
            MFMA_(0);
            __builtin_amdgcn_s_barrier();
            if (!m1) break;
        }
        {   // phase B: compute buf1 = tile kt+64
            const bool m2 = kt + 128 < KC;
            if (m2) { LOADB_A(kt + 128); STAGEA_(0, kt + 128); }
            if (m2) asm volatile("s_waitcnt vmcnt(4)" ::: "memory");
            else    asm volatile("s_waitcnt vmcnt(0)" ::: "memory");
            WRITEB_(1, xb0, xb1);
            asm volatile("s_waitcnt lgkmcnt(0)" ::: "memory");
            __builtin_amdgcn_s_barrier();
            MFMA_(1);
            __builtin_amdgcn_s_barrier();
            if (!m2) break;
        }
    }
#undef LOADB_A
#undef LOADB_B
#undef STAGEA_
#undef WRITEB_
#undef MFMA_
    // epilogue: C/D layout col=lane&15, row=(lane>>4)*4+reg
    const int cr = wm + gq * 4;
    const int cc = wn + fr;
#pragma unroll
    for (int mi = 0; mi < 2; mi++)
#pragma unroll
        for (int ni = 0; ni < 2; ni++)
#pragma unroll
            for (int j = 0; j < 4; j++)
                C[(size_t)(m0 + cr + mi * 16 + j) * D_ + (n0 + cc + ni * 16)] = acc[mi][ni][j];
}

__global__ __launch_bounds__(512) void gemm4g_kernel(const u16* __restrict__ x5, const float* __restrict__ Wk,
                                                     const float* __restrict__ Wv, const float* __restrict__ Wr,
                                                     const float* __restrict__ Wg, float* __restrict__ kvK,
                                                     float* __restrict__ kvV, float* __restrict__ kvR,
                                                     float* __restrict__ kvG)
{
    const int s = blockIdx.z;    // 0:k 1:v 2:r 3:g
    const u16* A = x5 + (size_t)(s == 0 ? 0 : s + 1) * M_ * D_;
    const float* W = (s == 0) ? Wk : (s == 1) ? Wv : (s == 2) ? Wr : Wg;
    float* C = (s == 0) ? kvK : (s == 1) ? kvV : (s == 2) ? kvR : kvG;
    gemm2p_body(A, W, C, blockIdx.y * 128, blockIdx.x * 64, 0, D_);
}

// gemm1: z = ks 0..3 (split-K 4, KC=512)
__global__ __launch_bounds__(512) void gemm1g_kernel(const u16* __restrict__ y, const float* __restrict__ wo,
                                                     float* __restrict__ out, float* __restrict__ pp1)
{
    const int ks = blockIdx.z;
    float* C = (ks == 0) ? out : pp1 + (size_t)(ks - 1) * M_ * D_;
    gemm2p_body(y, wo, C, blockIdx.y * 128, blockIdx.x * 64, ks * 512, 512);
}

__global__ __launch_bounds__(256) void add3_kernel(float* __restrict__ dst, const float* __restrict__ pp1)
{
    const size_t e = ((size_t)blockIdx.x * 256 + threadIdx.x) * 4;
    const size_t MD = (size_t)M_ * D_;
    f32x4 d = *(const f32x4*)(dst + e);
#pragma unroll
    for (int i = 0; i < 3; i++) {
        f32x4 a = *(const f32x4*)(pp1 + (size_t)i * MD + e);
#pragma unroll
        for (int j = 0; j < 4; j++) d[j] += a[j];
    }
    *(f32x4*)(dst + e) = d;
}

// ================ recurrence: chunked linear scan ================
__global__ __launch_bounds__(512) void rec1_kernel(const float* __restrict__ rB, const float* __restrict__ kB,
                                                   const float* __restrict__ wB, const float* __restrict__ vB,
                                                   const float* __restrict__ fa, float* __restrict__ rwkv,
                                                   float* __restrict__ CS, float* __restrict__ RP,
                                                   float* __restrict__ PC)
{
    const int bx = blockIdx.x;            // (b*32+h)*16 + c
    const int c  = bx & (NC_ - 1);
    const int bh = bx >> 4;
    const int h = bh & 31, b = bh >> 5;
    const int tid = threadIdx.x;
    const int wv = tid >> 6, lane = tid & 63;
    const int wg = wv >> 2;
    const int jb = lane >> 3, dsub = lane & 7;
    const int jbase = jb * 8;
    const int d0 = wg * 32 + (wv & 3) * 8 + dsub;

    __shared__ float stage[4][CL_][64];   // 16 KB
    __shared__ float p2[CL_][8][64];      // 32 KB
    __shared__ float p1[CL_][8];
    __shared__ float rpS[CL_ * 64];       // 4 KB

    float S[8], pv[8], faj[8];
#pragma unroll
    for (int q = 0; q < 8; q++) { S[q] = 0.f; pv[q] = 1.f; faj[q] = fa[h * 64 + jbase + q]; }

    const size_t base = ((size_t)b * T_ * H_ + h) * HS_;
    const int t0 = c * CL_;
    const int arr = wv & 3;
    const float* mysrc = (arr == 0) ? rB : (arr == 1) ? kB : (arr == 2) ? wB : vB;
    const int ts0 = wg * 8 + (lane >> 4);
    const int sch = (lane & 15) * 4;
    const bool p1w = (wv == 0 && dsub == 0);

#pragma unroll
    for (int p = 0; p < 2; p++) {
        f32x4 v = *(const f32x4*)(mysrc + base + (size_t)(t0 + ts0 + p * 4) * (H_ * HS_) + sch);
        *(f32x4*)&stage[arr][ts0 + p * 4][sch] = v;
    }
    __syncthreads();

    f32x4 r0 = *(const f32x4*)&stage[0][0][jbase];
    f32x4 r1 = *(const f32x4*)&stage[0][0][jbase + 4];
    f32x4 k0 = *(const f32x4*)&stage[1][0][jbase];
    f32x4 k1 = *(const f32x4*)&stage[1][0][jbase + 4];
    f32x4 w0 = *(const f32x4*)&stage[2][0][jbase];
    f32x4 w1 = *(const f32x4*)&stage[2][0][jbase + 4];
    float vd = stage[3][0][d0];
#pragma unroll
    for (int ts = 0; ts < CL_; ++ts) {
        f32x4 nr0 = r0, nr1 = r1, nk0 = k0, nk1 = k1, nw0 = w0, nw1 = w1;
        float nvd = vd;
        if (ts + 1 < CL_) {
            nr0 = *(const f32x4*)&stage[0][ts + 1][jbase];
            nr1 = *(const f32x4*)&stage[0][ts + 1][jbase + 4];
            nk0 = *(const f32x4*)&stage[1][ts + 1][jbase];
            nk1 = *(const f32x4*)&stage[1][ts + 1][jbase + 4];
            nw0 = *(const f32x4*)&stage[2][ts + 1][jbase];
            nw1 = *(const f32x4*)&stage[2][ts + 1][jbase + 4];
            nvd = stage[3][ts + 1][d0];
        }
        float s1 = 0.f, s2 = 0.f;
#pragma unroll
        for (int q = 0; q < 4; q++) {
            s1 = fmaf(r0[q] * faj[q],     k0[q], s1);
            s1 = fmaf(r1[q] * faj[q + 4], k1[q], s1);
            s2 = fmaf(r0[q], S[q],     s2);
            s2 = fmaf(r1[q], S[q + 4], s2);
        }
        p2[ts][jb][d0 ^ (jb << 3)] = s2;
        if (p1w) {
            p1[ts][jb] = s1;
#pragma unroll
            for (int q = 0; q < 4; q++) {
                rpS[ts * 64 + jbase + q]     = r0[q] * pv[q];
                rpS[ts * 64 + jbase + 4 + q] = r1[q] * pv[q + 4];
            }
        }
#pragma unroll
        for (int q = 0; q < 4; q++) {
            pv[q]     *= w0[q];
            pv[q + 4] *= w1[q];
            S[q]       = fmaf(w0[q], S[q],     k0[q] * vd);
            S[q + 4]   = fmaf(w1[q], S[q + 4], k1[q] * vd);
        }
        r0 = nr0; r1 = nr1; k0 = nk0; k1 = nk1; w0 = nw0; w1 = nw1; vd = nvd;
    }
    __syncthreads();   // p2/p1/rpS complete
#pragma unroll
    for (int p = 0; p < 2; p++) {
        const int ts = wv * 2 + p;
        f32x4 p1a = *(const f32x4*)&p1[ts][0];
        f32x4 p1b = *(const f32x4*)&p1[ts][4];
        float s1t = ((p1a[0] + p1a[1]) + (p1a[2] + p1a[3])) +
                    ((p1b[0] + p1b[1]) + (p1b[2] + p1b[3]));
        float s2t = 0.f;
#pragma unroll
        for (int j = 0; j < 8; j++) s2t += p2[ts][j][lane ^ (j << 3)];
        const float vvv = stage[3][ts][lane];
        rwkv[base + (size_t)(t0 + ts) * (H_ * HS_) + lane] = fmaf(vvv, s1t, s2t);
    }
    RP[(size_t)bx * (CL_ * 64) + tid]       = rpS[tid];
    RP[(size_t)bx * (CL_ * 64) + 512 + tid] = rpS[512 + tid];
#pragma unroll
    for (int q = 0; q < 8; q++)
        CS[(size_t)bx * 4096 + (size_t)(jbase + q) * 64 + d0] = S[q];
    if (p1w) {
#pragma unroll
        for (int q = 0; q < 8; q++)
            PC[(size_t)bx * 64 + jbase + q] = pv[q];
    }
}

// rec2: sequential over chunks: Sstart_{c+1} = CS_c + PC_c * Sstart_c; CS[c] <- Sstart_c
__global__ __launch_bounds__(512) void rec2_kernel(const float* __restrict__ state, const int* __restrict__ ip,
                                                   float* __restrict__ CS, const float* __restrict__ PC)
{
    const int bh = blockIdx.x;            // b*32+h
    const int b = bh >> 5, h = bh & 31;
    const int tid = threadIdx.x;
    const int o = tid * 8;
    const int jrow = tid >> 3;
    const float* Sp = state + (size_t)b * ST_ * D_ + (size_t)(66 * ip[0] + 2) * D_ + (size_t)h * HS_ * HS_;
    f32x4 c0 = *(const f32x4*)(Sp + o);
    f32x4 c1 = *(const f32x4*)(Sp + o + 4);
    for (int c = 0; c < NC_; ++c) {
        float* cs = CS + ((size_t)(bh * NC_ + c)) * 4096 + o;
        f32x4 l0 = *(const f32x4*)cs;
        f32x4 l1 = *(const f32x4*)(cs + 4);
        const float pc = PC[(size_t)(bh * NC_ + c) * 64 + jrow];
        f32x4 n0, n1;
#pragma unroll
        for (int i = 0; i < 4; i++) { n0[i] = fmaf(pc, c0[i], l0[i]); n1[i] = fmaf(pc, c1[i], l1[i]); }
        *(f32x4*)cs = c0;
        *(f32x4*)(cs + 4) = c1;
        c0 = n0; c1 = n1;
    }
}

// rec3gn: val = rwkv_partial + rp.Sstart, then fused groupnorm + silu gate -> y (bf16)
__global__ __launch_bounds__(256) void rec3gn_kernel(const float* __restrict__ CS, const float* __restrict__ RP,
                                                     const float* __restrict__ rwkv, const float* __restrict__ gpre,
                                                     const float* __restrict__ lnxw, const float* __restrict__ lnxb,
                                                     u16* __restrict__ y)
{
    const int bx = blockIdx.x;            // (b*32+h)*16 + c
    const int c  = bx & (NC_ - 1);
    const int bh = bx >> 4;
    const int h = bh & 31, b = bh >> 5;
    const int tid = threadIdx.x;
    __shared__ float Ss[4096];            // [j][d]
    __shared__ float rp[CL_ * 64];        // [tl][j]
#pragma unroll
    for (int i = 0; i < 4; i++)
        *(f32x4*)&Ss[tid * 4 + i * 1024] = *(const f32x4*)(CS + (size_t)bx * 4096 + tid * 4 + i * 1024);
    *(f32x4*)&rp[tid * 4] = *(const f32x4*)(RP + (size_t)bx * (CL_ * 64) + tid * 4);
    __syncthreads();
    const int tl = tid >> 4;              // 0..15 (local t)
    const int d4 = (tid & 15) * 4;
    f32x4 acc; acc[0] = acc[1] = acc[2] = acc[3] = 0.f;
    const float* rpr = &rp[tl * 64];
#pragma unroll 16
    for (int j = 0; j < 64; ++j) {
        const float rv = rpr[j];
        const f32x4 sv = *(const f32x4*)&Ss[j * 64 + d4];
#pragma unroll
        for (int i = 0; i < 4; i++) acc[i] = fmaf(rv, sv[i], acc[i]);
    }
    const size_t base = ((size_t)b * T_ * H_ + h) * HS_;
    const size_t eb = base + (size_t)(c * CL_ + tl) * (H_ * HS_);
    const f32x4 cur = *(const f32x4*)(rwkv + eb + d4);
    f32x4 val;
#pragma unroll
    for (int i = 0; i < 4; i++) val[i] = cur[i] + acc[i];
    float s = 0.f, q = 0.f;
#pragma unroll
    for (int i = 0; i < 4; i++) { s += val[i]; q += val[i] * val[i]; }
#pragma unroll
    for (int off = 1; off < 16; off <<= 1) { s += __shfl_xor(s, off, 64); q += __shfl_xor(q, off, 64); }
    const float mu = s * (1.f / 64.f);
    const float var = q * (1.f / 64.f) - mu * mu;
    const float rs = rsqrtf(var + EPS_);
    bf16x4 yv;
#pragma unroll
    for (int i = 0; i < 4; i++) {
        const int hj = h * 64 + d4 + i;
        const float nrm = (val[i] - mu) * rs * lnxw[hj] + lnxb[hj];
        const float gp = gpre[eb + d4 + i];
        const float gv = gp / (1.f + expf(-gp));
        yv[i] = (short)f2bf(nrm * gv);
    }
    *(bf16x4*)(y + eb + d4) = yv;
}

extern "C" void kernel_launch(void* const* d_in, const int* in_sizes, int n_in,
                              void* d_out, int out_size, void* d_ws, size_t ws_size,
                              hipStream_t stream)
{
    const float* x     = (const float*)d_in[0];
    const float* state = (const float*)d_in[1];
    const float* ln1w  = (const float*)d_in[2];
    const float* ln1b  = (const float*)d_in[3];
    const float* maax  = (const float*)d_in[4];
    const float* w1    = (const float*)d_in[5];
    const float* w2    = (const float*)d_in[6];
    const float* maak  = (const float*)d_in[7];
    const float* maaw  = (const float*)d_in[8];
    const float* maav  = (const float*)d_in[9];
    const float* maar  = (const float*)d_in[10];
    const float* maag  = (const float*)d_in[11];
    const float* tdec  = (const float*)d_in[12];
    const float* dw1   = (const float*)d_in[13];
    const float* dw2   = (const float*)d_in[14];
    const float* fa    = (const float*)d_in[15];
    const float* wrec  = (const float*)d_in[16];
    const float* wkey  = (const float*)d_in[17];
    const float* wval  = (const float*)d_in[18];
    const float* wout  = (const float*)d_in[19];
    const float* wgate = (const float*)d_in[20];
    const float* lnxw  = (const float*)d_in[21];
    const float* lnxb  = (const float*)d_in[22];
    const int*   ip    = (const int*)d_in[23];

    char* ws = (char*)d_ws;
    const size_t MD = (size_t)M_ * D_;
    // lifetime-packed layout (78 MB budget)
    float* CS   = (float*)(ws);                          // [0,16)  rec phase
    float* RP   = (float*)(ws + ((size_t)16 << 20));     // [16,20)
    float* PC   = (float*)(ws + ((size_t)20 << 20));     // [20,20.25)
    float* pp1  = (float*)(ws);                          // [0,12) during gemm1g (CS/RP dead)
    float* xln  = (float*)(ws + ((size_t)40 << 20));     // [40,44)  dead after maa2
    float* sx   = (float*)(ws + ((size_t)44 << 20));     // [44,48)  dead after maa2
    u16*   xxxb = (u16*)  (ws + ((size_t)48 << 20));     // [48,50)  dead after wdot-maa1
    u16*   w1t  = (u16*)  (ws + ((size_t)50 << 20));     // [50,51)  dead after wdot-maa1
    u16*   dw1t = (u16*)  (ws + ((size_t)51 << 20));     // [51,52)  dead after wdot-decay1
    float* t5   = (float*)(ws + ((size_t)52 << 20));     // [52,53)  dead after maa2
    float* td   = (float*)(ws + ((size_t)53 << 20));     // [53,54)  dead after decay2
    u16*   x5   = (u16*)  (ws + ((size_t)54 << 20));     // [54,64)  dead after gemm4g
    float* wdec = (float*)(ws + ((size_t)64 << 20));     // [64,68)  dead after rec1
    float* kvK  = (float*)(ws + ((size_t)40 << 20));     // aliases xln  (dead)
    float* kvV  = (float*)(ws + ((size_t)44 << 20));     // aliases sx   (dead)
    float* kvR  = (float*)(ws + ((size_t)48 << 20));     // aliases xxxb/w1t/dw1t (dead)
    float* kvG  = (float*)(ws + ((size_t)68 << 20));     // [68,72)
    float* rwkv = (float*)(ws + ((size_t)72 << 20));     // [72,76)
    u16*   y    = (u16*)  (ws + ((size_t)76 << 20));     // [76,78)
    float* out  = (float*)d_out;

    hipLaunchKernelGGL(ln_kernel,     dim3(512),      dim3(256), 0, stream, x, ln1w, ln1b, xln);
    hipLaunchKernelGGL(shift_kernel,  dim3(1024),     dim3(256), 0, stream, xln, state, maax, ip, sx, xxxb);
    hipLaunchKernelGGL(txp_kernel,    dim3(64, 5),    dim3(256), 0, stream, w1, w1t, D_, 160);
    hipLaunchKernelGGL(txp_kernel,    dim3(64, 2),    dim3(256), 0, stream, dw1, dw1t, D_, 64);
    hipLaunchKernelGGL((wdot_kernel<true>), dim3(10240), dim3(512), 0, stream, xxxb, w1t, t5, 160);
    hipLaunchKernelGGL(maa2_kernel,   dim3(1024),     dim3(256), 0, stream, t5, w2, xln, sx, maak, maaw, maav, maar, maag, x5);
    hipLaunchKernelGGL((wdot_kernel<true>), dim3(4096), dim3(512), 0, stream, x5 + MD, dw1t, td, 64);
    hipLaunchKernelGGL(decay2_kernel, dim3(1024),     dim3(256), 0, stream, td, dw2, tdec, wdec);
    hipLaunchKernelGGL(gemm4g_kernel, dim3(32, 4, 4), dim3(512), 0, stream, x5, wkey, wval, wrec, wgate, kvK, kvV, kvR, kvG);
    hipLaunchKernelGGL(rec1_kernel,   dim3(B_ * H_ * NC_), dim3(512), 0, stream, kvR, kvK, wdec, kvV, fa, rwkv, CS, RP, PC);
    hipLaunchKernelGGL(rec2_kernel,   dim3(B_ * H_),  dim3(512), 0, stream, state, ip, CS, PC);
    hipLaunchKernelGGL(rec3gn_kernel, dim3(B_ * H_ * NC_), dim3(256), 0, stream, CS, RP, rwkv, kvG, lnxw, lnxb, y);
    hipLaunchKernelGGL(gemm1g_kernel, dim3(32, 4, 4), dim3(512), 0, stream, y, wout, out, pp1);
    hipLaunchKernelGGL(add3_kernel,   dim3(1024),     dim3(256), 0, stream, out, pp1);

    (void)in_sizes; (void)n_in; (void)out_size; (void)ws_size;
}

// Round 16
// 172.678 us; speedup vs baseline: 1.3546x; 1.0131x over previous
//
#include <hip/hip_runtime.h>
#include <hip/hip_bf16.h>

typedef unsigned short u16;
typedef __attribute__((ext_vector_type(4))) float f32x4;
typedef __attribute__((ext_vector_type(8))) short short8;  // 8 bf16 raw bits
typedef __attribute__((ext_vector_type(4))) short bf16x4;

#define B_ 2
#define T_ 256
#define D_ 2048
#define H_ 32
#define HS_ 64
#define M_ 512          // B*T
#define ST_ 66
#define EPS_ 1e-5f
#define NC_ 16          // recurrence chunks
#define CL_ 16          // chunk length

__device__ __forceinline__ float bf2f(u16 u) {
    union { unsigned int i; float f; } c; c.i = ((unsigned int)u) << 16; return c.f;
}
__device__ __forceinline__ u16 f2bf(float f) {
    union { unsigned int i; float f; } c; c.f = f;
    unsigned int r = c.i + 0x7fffu + ((c.i >> 16) & 1u);   // round-to-nearest-even
    return (u16)(r >> 16);
}
__device__ __forceinline__ u16 f2bf_hw(float f) {
    __hip_bfloat16 b = __float2bfloat16(f);
    return *reinterpret_cast<u16*>(&b);
}

__device__ __forceinline__ void gld16(const u16* g, u16* l) {
    __builtin_amdgcn_global_load_lds((const __attribute__((address_space(1))) void*)g,
                                     (__attribute__((address_space(3))) void*)l, 16, 0, 0);
}

// ---------------- LayerNorm: x -> xln ----------------
__global__ __launch_bounds__(256) void ln_kernel(const float* __restrict__ x, const float* __restrict__ w,
                                                 const float* __restrict__ bias, float* __restrict__ xln)
{
    const int row = blockIdx.x;                 // 0..511
    const float* xr = x + (size_t)row * D_;
    float* orow = xln + (size_t)row * D_;
    const int t = threadIdx.x;
    f32x4 a0 = *(const f32x4*)(xr + t * 8);
    f32x4 a1 = *(const f32x4*)(xr + t * 8 + 4);
    float s = 0.f, q = 0.f;
#pragma unroll
    for (int i = 0; i < 4; i++) { s += a0[i] + a1[i]; q += a0[i]*a0[i] + a1[i]*a1[i]; }
#pragma unroll
    for (int off = 1; off < 64; off <<= 1) { s += __shfl_xor(s, off, 64); q += __shfl_xor(q, off, 64); }
    __shared__ float ls[4], lq[4];
    const int wid = t >> 6, lane = t & 63;
    if (lane == 0) { ls[wid] = s; lq[wid] = q; }
    __syncthreads();
    s = ls[0] + ls[1] + ls[2] + ls[3];
    q = lq[0] + lq[1] + lq[2] + lq[3];
    const float mu = s * (1.f / D_);
    const float var = q * (1.f / D_) - mu * mu;
    const float rs = rsqrtf(var + EPS_);
#pragma unroll
    for (int i = 0; i < 8; i++) {
        int d = t * 8 + i;
        float f = (i < 4) ? a0[i] : a1[i - 4];
        orow[d] = (f - mu) * rs * w[d] + bias[d];
    }
}

// ---------------- token shift: sx = prev - cur ; xxxb = bf16(xln + sx*maa_x) ----------------
__global__ __launch_bounds__(256) void shift_kernel(const float* __restrict__ xln, const float* __restrict__ state,
                                                    const float* __restrict__ maax, const int* __restrict__ ip,
                                                    float* __restrict__ sx, u16* __restrict__ xxxb)
{
    const size_t gid = (size_t)blockIdx.x * 256 + threadIdx.x;
    const size_t e = gid * 4;                   // 4 floats per thread
    const int row = (int)(e >> 11);
    const int d = (int)(e & 2047);
    const int tt = row & (T_ - 1);
    const int b = row >> 8;
    const float* prev;
    if (tt == 0) prev = state + ((size_t)b * ST_ + (size_t)(66 * ip[0] + 1)) * D_ + d;
    else         prev = xln + e - D_;
    f32x4 p = *(const f32x4*)prev;
    f32x4 c = *(const f32x4*)(xln + e);
    f32x4 mx = *(const f32x4*)(maax + d);
    f32x4 sv;
    bf16x4 xv;
#pragma unroll
    for (int i = 0; i < 4; i++) { sv[i] = p[i] - c[i]; xv[i] = (short)f2bf(c[i] + sv[i] * mx[i]); }
    *(f32x4*)(sx + e) = sv;
    *(bf16x4*)(xxxb + e) = xv;
}

// ---------------- transpose + bf16: out[n][k] = bf16(in[k][n]) ----------------
__global__ __launch_bounds__(256) void txp_kernel(const float* __restrict__ in, u16* __restrict__ out,
                                                  int K, int N)
{
    __shared__ float tile[32][33];
    const int k0 = blockIdx.x * 32, n0 = blockIdx.y * 32;
    const int c = threadIdx.x & 31, r8 = threadIdx.x >> 5;   // 0..7
#pragma unroll
    for (int i = 0; i < 4; i++) {
        int r = r8 + i * 8;
        tile[r][c] = in[(size_t)(k0 + r) * N + (n0 + c)];
    }
    __syncthreads();
#pragma unroll
    for (int i = 0; i < 4; i++) {
        int r = r8 + i * 8;
        out[(size_t)(n0 + r) * K + (k0 + c)] = f2bf(tile[c][r]);
    }
}

// ---------------- wave-dot GEMM: one wave per output, C[m,n] = act(A[m,:] . Wt[n,:]) ----------------
template<bool TANH>
__global__ __launch_bounds__(512) void wdot_kernel(const u16* __restrict__ A, const u16* __restrict__ Wt,
                                                   float* __restrict__ C, int N)
{
    const int gw = (int)((blockIdx.x * 512 + threadIdx.x) >> 6);  // global wave id
    const int lane = threadIdx.x & 63;
    const int m = gw / N, n = gw - m * N;
    const u16* a = A + (size_t)m * D_ + lane * 8;
    const u16* w = Wt + (size_t)n * D_ + lane * 8;
    float acc = 0.f;
#pragma unroll
    for (int i = 0; i < 4; i++) {
        short8 av = *(const short8*)(a + i * 512);
        short8 wv = *(const short8*)(w + i * 512);
#pragma unroll
        for (int j = 0; j < 8; j++)
            acc = fmaf(bf2f((u16)av[j]), bf2f((u16)wv[j]), acc);
    }
#pragma unroll
    for (int off = 1; off < 64; off <<= 1) acc += __shfl_xor(acc, off, 64);
    if (lane == 0) C[gw] = TANH ? tanhf(acc) : acc;
}

// ---------------- maa lora stage 2 + x5 build: all 5 f per thread, xln/sx read once ----------------
__global__ __launch_bounds__(256) void maa2_kernel(const float* __restrict__ t5, const float* __restrict__ w2,
                                                   const float* __restrict__ xln, const float* __restrict__ sxp,
                                                   const float* __restrict__ mk, const float* __restrict__ mw,
                                                   const float* __restrict__ mv, const float* __restrict__ mr,
                                                   const float* __restrict__ mg, u16* __restrict__ x5)
{
    const int gid = blockIdx.x * 256 + threadIdx.x;   // 2048*128
    const int d = gid & (D_ - 1);
    const int mg4 = gid >> 11;                        // 0..127
    const size_t m0 = (size_t)mg4 * 4;
    float xl[4], sv[4];
#pragma unroll
    for (int mm = 0; mm < 4; mm++) {
        const size_t e = (m0 + mm) * D_ + d;
        xl[mm] = xln[e];
        sv[mm] = sxp[e];
    }
    const float* t5b = t5 + m0 * 160;
#pragma unroll
    for (int f = 0; f < 5; f++) {
        const float* maa = (f == 0) ? mk : (f == 1) ? mw : (f == 2) ? mv : (f == 3) ? mr : mg;
        const float mf = maa[d];
        const float* w2f = w2 + (size_t)f * 32 * D_ + d;
        float a0 = 0, a1 = 0, a2 = 0, a3 = 0;
#pragma unroll 8
        for (int r = 0; r < 32; r++) {
            const float wv = w2f[(size_t)r * D_];
            a0 = fmaf(t5b[f * 32 + r], wv, a0);
            a1 = fmaf(t5b[160 + f * 32 + r], wv, a1);
            a2 = fmaf(t5b[320 + f * 32 + r], wv, a2);
            a3 = fmaf(t5b[480 + f * 32 + r], wv, a3);
        }
        const float accs[4] = {a0, a1, a2, a3};
#pragma unroll
        for (int mm = 0; mm < 4; mm++) {
            const size_t e = (m0 + mm) * D_ + d;
            x5[(size_t)f * M_ * D_ + e] = f2bf(xl[mm] + sv[mm] * (mf + accs[mm]));
        }
    }
}

// ---------------- decay lora stage 2: w = exp(-exp(time_decay + td @ dw2)) ----------------
__global__ __launch_bounds__(256) void decay2_kernel(const float* __restrict__ td, const float* __restrict__ dw2,
                                                     const float* __restrict__ tdec, float* __restrict__ wout)
{
    const int gid = blockIdx.x * 256 + threadIdx.x;   // 2048*128
    const int d = gid & (D_ - 1);
    const int mg4 = gid >> 11;                        // 0..127
    const float* wp = dw2 + d;
    const float* tb = td + (size_t)mg4 * 4 * 64;
    float a0 = 0, a1 = 0, a2 = 0, a3 = 0;
#pragma unroll 8
    for (int r = 0; r < 64; r++) {
        float wv = wp[(size_t)r * D_];
        a0 = fmaf(tb[r], wv, a0);
        a1 = fmaf(tb[64 + r], wv, a1);
        a2 = fmaf(tb[128 + r], wv, a2);
        a3 = fmaf(tb[192 + r], wv, a3);
    }
    const float base = tdec[d];
    const float accs[4] = {a0, a1, a2, a3};
#pragma unroll
    for (int mm = 0; mm < 4; mm++)
        wout[((size_t)mg4 * 4 + mm) * D_ + d] = expf(-expf(base + accs[mm]));
}

// ---------------- bf16 GEMM: 128x64 tile, BK=64, 512 threads, depth-2 pipeline (3 buffers) ----------------
// A via global_load_lds + XOR swizzle (0-conflict); B = f32 reg-staged -> bf16 -> LDS.
// Phase t issues tile t+2; vmcnt(8) waits only tile t (2 tiles stay in flight across barriers).
__device__ __forceinline__ void gemm2p_body(const u16* __restrict__ A, const float* __restrict__ Wf,
                                            float* __restrict__ C, int m0, int n0, int k0, int KC)
{
    __shared__ u16 As[3][128 * 64];   // 48 KB
    __shared__ u16 Bs[3][64 * 64];    // 24 KB
    const int tid = threadIdx.x;      // 0..511
    const int lane = tid & 63;
    const int wvid = tid >> 6;        // 0..7
    const int wm = (wvid >> 1) * 32;  // 0,32,64,96
    const int wn = (wvid & 1) * 32;   // 0,32

    f32x4 acc[2][2];
#pragma unroll
    for (int i = 0; i < 2; i++)
#pragma unroll
        for (int j = 0; j < 2; j++) { acc[i][j][0]=0.f; acc[i][j][1]=0.f; acc[i][j][2]=0.f; acc[i][j][3]=0.f; }

    // A staging: rows srow, srow+64; dest chunk schk; source chunk pre-swizzled (rule #21)
    const int srow = tid >> 3;                       // 0..63
    const int schk = tid & 7;                        // 0..7
    const u16* Ag = A + (size_t)(m0 + srow) * D_ + k0 + ((schk ^ (srow & 7)) << 3);
    const int ldst = tid * 8;                        // = srow*64 + schk*8

    // B staging: row srow, f32 cols schk*8..+8 -> one short8 at swizzled chunk
    const float* Wg = Wf + (size_t)(n0 + srow) * D_ + k0 + schk * 8;
    const int bdst = srow * 64 + ((schk ^ (srow & 7)) << 3);

    // read-side: chunk g of row r lives at g ^ (r&7)
    const int fr = lane & 15;
    const int gq = lane >> 4;

    const int NT = KC >> 6;   // tiles of 64

    // named B-register triple sets (rule #20)
    f32x4 xa0, xa1, xb0, xb1, xc0, xc1;

#define LOADB_0(kt) { xa0 = *(const f32x4*)(Wg + (kt)); xa1 = *(const f32x4*)(Wg + (kt) + 4); }
#define LOADB_1(kt) { xb0 = *(const f32x4*)(Wg + (kt)); xb1 = *(const f32x4*)(Wg + (kt) + 4); }
#define LOADB_2(kt) { xc0 = *(const f32x4*)(Wg + (kt)); xc1 = *(const f32x4*)(Wg + (kt) + 4); }
#define STAGEA_(bb, kt)                                                           \
    {                                                                             \
        gld16(Ag + (kt), &As[bb][ldst]);                                          \
        gld16(Ag + (size_t)64 * D_ + (kt), &As[bb][4096 + ldst]);                 \
    }
#define WRITEB_(bb, r0, r1)                                                       \
    {                                                                             \
        short8 p0;                                                                \
        _Pragma("unroll")                                                         \
        for (int j = 0; j < 4; j++) {                                             \
            p0[j]     = (short)f2bf_hw(r0[j]);                                    \
            p0[j + 4] = (short)f2bf_hw(r1[j]);                                    \
        }                                                                         \
        *(short8*)&Bs[bb][bdst] = p0;                                             \
    }
#define MFMA_(bb)                                                                 \
    {                                                                             \
        _Pragma("unroll")                                                         \
        for (int kk = 0; kk < 2; kk++) {                                          \
            short8 av[2], bv[2];                                                  \
            _Pragma("unroll")                                                     \
            for (int mi = 0; mi < 2; mi++) {                                      \
                const int row = wm + mi * 16 + fr;                                \
                const int g = (gq + kk * 4) ^ (row & 7);                          \
                av[mi] = *(const short8*)&As[bb][row * 64 + g * 8];               \
            }                                                                     \
            _Pragma("unroll")                                                     \
            for (int ni = 0; ni < 2; ni++) {                                      \
                const int row = wn + ni * 16 + fr;                                \
                const int g = (gq + kk * 4) ^ (row & 7);                          \
                bv[ni] = *(const short8*)&Bs[bb][row * 64 + g * 8];               \
            }                                                                     \
            _Pragma("unroll")                                                     \
            for (int mi = 0; mi < 2; mi++)                                        \
            _Pragma("unroll")                                                     \
            for (int ni = 0; ni < 2; ni++)                                        \
                acc[mi][ni] = __builtin_amdgcn_mfma_f32_16x16x32_bf16(av[mi], bv[ni], acc[mi][ni], 0, 0, 0); \
        }                                                                         \
    }
// phase for tile t in buffer bb; issues tile t+2 into buffer bn (reg set LOADN)
#define PHASE_(bb, bn, LOADN, W0, W1, t, kt)                                      \
    {                                                                             \
        const bool more2 = (t) + 2 < NT;                                          \
        if (more2) { LOADN((kt) + 128); STAGEA_(bn, (kt) + 128); }                \
        if (more2)              asm volatile("s_waitcnt vmcnt(8)" ::: "memory");  \
        else if ((t) + 1 < NT)  asm volatile("s_waitcnt vmcnt(4)" ::: "memory");  \
        else                    asm volatile("s_waitcnt vmcnt(0)" ::: "memory");  \
        WRITEB_(bb, W0, W1);                                                      \
        asm volatile("s_waitcnt lgkmcnt(0)" ::: "memory");                        \
        __builtin_amdgcn_s_barrier();                                             \
        MFMA_(bb);                                                                \
        __builtin_amdgcn_s_barrier();                                             \
    }

    // prologue: issue tiles 0 and 1 (8 VMEM ops/thread in flight)
    LOADB_0(0);
    STAGEA_(0, 0);
    LOADB_1(64);
    STAGEA_(1, 64);
    int t = 0, kt = 0;
    while (t + 3 <= NT) {
        PHASE_(0, 2, LOADB_2, xa0, xa1, t,     kt);
        PHASE_(1, 0, LOADB_0, xb0, xb1, t + 1, kt + 64);
        PHASE_(2, 1, LOADB_1, xc0, xc1, t + 2, kt + 128);
        t += 3; kt += 192;
    }
    if (t < NT) { PHASE_(0, 2, LOADB_2, xa0, xa1, t, kt); t++; kt += 64; }
    if (t < NT) { PHASE_(1, 0, LOADB_0, xb0, xb1, t, kt); }
#undef LOADB_0
#undef LOADB_1
#undef LOADB_2
#undef STAGEA_
#undef WRITEB_
#undef MFMA_
#undef PHASE_
    // epilogue: C/D layout col=lane&15, row=(lane>>4)*4+reg
    const int cr = wm + gq * 4;
    const int cc = wn + fr;
#pragma unroll
    for (int mi = 0; mi < 2; mi++)
#pragma unroll
        for (int ni = 0; ni < 2; ni++)
#pragma unroll
            for (int j = 0; j < 4; j++)
                C[(size_t)(m0 + cr + mi * 16 + j) * D_ + (n0 + cc + ni * 16)] = acc[mi][ni][j];
}

__global__ __launch_bounds__(512) void gemm4g_kernel(const u16* __restrict__ x5, const float* __restrict__ Wk,
                                                     const float* __restrict__ Wv, const float* __restrict__ Wr,
                                                     const float* __restrict__ Wg, float* __restrict__ kvK,
                                                     float* __restrict__ kvV, float* __restrict__ kvR,
                                                     float* __restrict__ kvG)
{
    const int s = blockIdx.z;    // 0:k 1:v 2:r 3:g
    const u16* A = x5 + (size_t)(s == 0 ? 0 : s + 1) * M_ * D_;
    const float* W = (s == 0) ? Wk : (s == 1) ? Wv : (s == 2) ? Wr : Wg;
    float* C = (s == 0) ? kvK : (s == 1) ? kvV : (s == 2) ? kvR : kvG;
    gemm2p_body(A, W, C, blockIdx.y * 128, blockIdx.x * 64, 0, D_);
}

// gemm1: z = ks 0..3 (split-K 4, KC=512)
__global__ __launch_bounds__(512) void gemm1g_kernel(const u16* __restrict__ y, const float* __restrict__ wo,
                                                     float* __restrict__ out, float* __restrict__ pp1)
{
    const int ks = blockIdx.z;
    float* C = (ks == 0) ? out : pp1 + (size_t)(ks - 1) * M_ * D_;
    gemm2p_body(y, wo, C, blockIdx.y * 128, blockIdx.x * 64, ks * 512, 512);
}

__global__ __launch_bounds__(256) void add3_kernel(float* __restrict__ dst, const float* __restrict__ pp1)
{
    const size_t e = ((size_t)blockIdx.x * 256 + threadIdx.x) * 4;
    const size_t MD = (size_t)M_ * D_;
    f32x4 d = *(const f32x4*)(dst + e);
#pragma unroll
    for (int i = 0; i < 3; i++) {
        f32x4 a = *(const f32x4*)(pp1 + (size_t)i * MD + e);
#pragma unroll
        for (int j = 0; j < 4; j++) d[j] += a[j];
    }
    *(f32x4*)(dst + e) = d;
}

// ================ recurrence: chunked linear scan ================
__global__ __launch_bounds__(512) void rec1_kernel(const float* __restrict__ rB, const float* __restrict__ kB,
                                                   const float* __restrict__ wB, const float* __restrict__ vB,
                                                   const float* __restrict__ fa, float* __restrict__ rwkv,
                                                   float* __restrict__ CS, float* __restrict__ RP,
                                                   float* __restrict__ PC)
{
    const int bx = blockIdx.x;            // (b*32+h)*16 + c
    const int c  = bx & (NC_ - 1);
    const int bh = bx >> 4;
    const int h = bh & 31, b = bh >> 5;
    const int tid = threadIdx.x;
    const int wv = tid >> 6, lane = tid & 63;
    const int wg = wv >> 2;
    const int jb = lane >> 3, dsub = lane & 7;
    const int jbase = jb * 8;
    const int d0 = wg * 32 + (wv & 3) * 8 + dsub;

    __shared__ float stage[4][CL_][64];   // 16 KB
    __shared__ float p2[CL_][8][64];      // 32 KB
    __shared__ float p1[CL_][8];
    __shared__ float rpS[CL_ * 64];       // 4 KB

    float S[8], pv[8], faj[8];
#pragma unroll
    for (int q = 0; q < 8; q++) { S[q] = 0.f; pv[q] = 1.f; faj[q] = fa[h * 64 + jbase + q]; }

    const size_t base = ((size_t)b * T_ * H_ + h) * HS_;
    const int t0 = c * CL_;
    const int arr = wv & 3;
    const float* mysrc = (arr == 0) ? rB : (arr == 1) ? kB : (arr == 2) ? wB : vB;
    const int ts0 = wg * 8 + (lane >> 4);
    const int sch = (lane & 15) * 4;
    const bool p1w = (wv == 0 && dsub == 0);

#pragma unroll
    for (int p = 0; p < 2; p++) {
        f32x4 v = *(const f32x4*)(mysrc + base + (size_t)(t0 + ts0 + p * 4) * (H_ * HS_) + sch);
        *(f32x4*)&stage[arr][ts0 + p * 4][sch] = v;
    }
    __syncthreads();

    f32x4 r0 = *(const f32x4*)&stage[0][0][jbase];
    f32x4 r1 = *(const f32x4*)&stage[0][0][jbase + 4];
    f32x4 k0 = *(const f32x4*)&stage[1][0][jbase];
    f32x4 k1 = *(const f32x4*)&stage[1][0][jbase + 4];
    f32x4 w0 = *(const f32x4*)&stage[2][0][jbase];
    f32x4 w1 = *(const f32x4*)&stage[2][0][jbase + 4];
    float vd = stage[3][0][d0];
#pragma unroll
    for (int ts = 0; ts < CL_; ++ts) {
        f32x4 nr0 = r0, nr1 = r1, nk0 = k0, nk1 = k1, nw0 = w0, nw1 = w1;
        float nvd = vd;
        if (ts + 1 < CL_) {
            nr0 = *(const f32x4*)&stage[0][ts + 1][jbase];
            nr1 = *(const f32x4*)&stage[0][ts + 1][jbase + 4];
            nk0 = *(const f32x4*)&stage[1][ts + 1][jbase];
            nk1 = *(const f32x4*)&stage[1][ts + 1][jbase + 4];
            nw0 = *(const f32x4*)&stage[2][ts + 1][jbase];
            nw1 = *(const f32x4*)&stage[2][ts + 1][jbase + 4];
            nvd = stage[3][ts + 1][d0];
        }
        float s1 = 0.f, s2 = 0.f;
#pragma unroll
        for (int q = 0; q < 4; q++) {
            s1 = fmaf(r0[q] * faj[q],     k0[q], s1);
            s1 = fmaf(r1[q] * faj[q + 4], k1[q], s1);
            s2 = fmaf(r0[q], S[q],     s2);
            s2 = fmaf(r1[q], S[q + 4], s2);
        }
        p2[ts][jb][d0 ^ (jb << 3)] = s2;
        if (p1w) {
            p1[ts][jb] = s1;
#pragma unroll
            for (int q = 0; q < 4; q++) {
                rpS[ts * 64 + jbase + q]     = r0[q] * pv[q];
                rpS[ts * 64 + jbase + 4 + q] = r1[q] * pv[q + 4];
            }
        }
#pragma unroll
        for (int q = 0; q < 4; q++) {
            pv[q]     *= w0[q];
            pv[q + 4] *= w1[q];
            S[q]       = fmaf(w0[q], S[q],     k0[q] * vd);
            S[q + 4]   = fmaf(w1[q], S[q + 4], k1[q] * vd);
        }
        r0 = nr0; r1 = nr1; k0 = nk0; k1 = nk1; w0 = nw0; w1 = nw1; vd = nvd;
    }
    __syncthreads();   // p2/p1/rpS complete
#pragma unroll
    for (int p = 0; p < 2; p++) {
        const int ts = wv * 2 + p;
        f32x4 p1a = *(const f32x4*)&p1[ts][0];
        f32x4 p1b = *(const f32x4*)&p1[ts][4];
        float s1t = ((p1a[0] + p1a[1]) + (p1a[2] + p1a[3])) +
                    ((p1b[0] + p1b[1]) + (p1b[2] + p1b[3]));
        float s2t = 0.f;
#pragma unroll
        for (int j = 0; j < 8; j++) s2t += p2[ts][j][lane ^ (j << 3)];
        const float vvv = stage[3][ts][lane];
        rwkv[base + (size_t)(t0 + ts) * (H_ * HS_) + lane] = fmaf(vvv, s1t, s2t);
    }
    RP[(size_t)bx * (CL_ * 64) + tid]       = rpS[tid];
    RP[(size_t)bx * (CL_ * 64) + 512 + tid] = rpS[512 + tid];
#pragma unroll
    for (int q = 0; q < 8; q++)
        CS[(size_t)bx * 4096 + (size_t)(jbase + q) * 64 + d0] = S[q];
    if (p1w) {
#pragma unroll
        for (int q = 0; q < 8; q++)
            PC[(size_t)bx * 64 + jbase + q] = pv[q];
    }
}

// rec2: sequential over chunks: Sstart_{c+1} = CS_c + PC_c * Sstart_c; CS[c] <- Sstart_c
__global__ __launch_bounds__(512) void rec2_kernel(const float* __restrict__ state, const int* __restrict__ ip,
                                                   float* __restrict__ CS, const float* __restrict__ PC)
{
    const int bh = blockIdx.x;            // b*32+h
    const int b = bh >> 5, h = bh & 31;
    const int tid = threadIdx.x;
    const int o = tid * 8;
    const int jrow = tid >> 3;
    const float* Sp = state + (size_t)b * ST_ * D_ + (size_t)(66 * ip[0] + 2) * D_ + (size_t)h * HS_ * HS_;
    f32x4 c0 = *(const f32x4*)(Sp + o);
    f32x4 c1 = *(const f32x4*)(Sp + o + 4);
    for (int c = 0; c < NC_; ++c) {
        float* cs = CS + ((size_t)(bh * NC_ + c)) * 4096 + o;
        f32x4 l0 = *(const f32x4*)cs;
        f32x4 l1 = *(const f32x4*)(cs + 4);
        const float pc = PC[(size_t)(bh * NC_ + c) * 64 + jrow];
        f32x4 n0, n1;
#pragma unroll
        for (int i = 0; i < 4; i++) { n0[i] = fmaf(pc, c0[i], l0[i]); n1[i] = fmaf(pc, c1[i], l1[i]); }
        *(f32x4*)cs = c0;
        *(f32x4*)(cs + 4) = c1;
        c0 = n0; c1 = n1;
    }
}

// rec3gn: val = rwkv_partial + rp.Sstart, then fused groupnorm + silu gate -> y (bf16)
__global__ __launch_bounds__(256) void rec3gn_kernel(const float* __restrict__ CS, const float* __restrict__ RP,
                                                     const float* __restrict__ rwkv, const float* __restrict__ gpre,
                                                     const float* __restrict__ lnxw, const float* __restrict__ lnxb,
                                                     u16* __restrict__ y)
{
    const int bx = blockIdx.x;            // (b*32+h)*16 + c
    const int c  = bx & (NC_ - 1);
    const int bh = bx >> 4;
    const int h = bh & 31, b = bh >> 5;
    const int tid = threadIdx.x;
    __shared__ float Ss[4096];            // [j][d]
    __shared__ float rp[CL_ * 64];        // [tl][j]
#pragma unroll
    for (int i = 0; i < 4; i++)
        *(f32x4*)&Ss[tid * 4 + i * 1024] = *(const f32x4*)(CS + (size_t)bx * 4096 + tid * 4 + i * 1024);
    *(f32x4*)&rp[tid * 4] = *(const f32x4*)(RP + (size_t)bx * (CL_ * 64) + tid * 4);
    __syncthreads();
    const int tl = tid >> 4;              // 0..15 (local t)
    const int d4 = (tid & 15) * 4;
    f32x4 acc; acc[0] = acc[1] = acc[2] = acc[3] = 0.f;
    const float* rpr = &rp[tl * 64];
#pragma unroll 16
    for (int j = 0; j < 64; ++j) {
        const float rv = rpr[j];
        const f32x4 sv = *(const f32x4*)&Ss[j * 64 + d4];
#pragma unroll
        for (int i = 0; i < 4; i++) acc[i] = fmaf(rv, sv[i], acc[i]);
    }
    const size_t base = ((size_t)b * T_ * H_ + h) * HS_;
    const size_t eb = base + (size_t)(c * CL_ + tl) * (H_ * HS_);
    const f32x4 cur = *(const f32x4*)(rwkv + eb + d4);
    f32x4 val;
#pragma unroll
    for (int i = 0; i < 4; i++) val[i] = cur[i] + acc[i];
    float s = 0.f, q = 0.f;
#pragma unroll
    for (int i = 0; i < 4; i++) { s += val[i]; q += val[i] * val[i]; }
#pragma unroll
    for (int off = 1; off < 16; off <<= 1) { s += __shfl_xor(s, off, 64); q += __shfl_xor(q, off, 64); }
    const float mu = s * (1.f / 64.f);
    const float var = q * (1.f / 64.f) - mu * mu;
    const float rs = rsqrtf(var + EPS_);
    bf16x4 yv;
#pragma unroll
    for (int i = 0; i < 4; i++) {
        const int hj = h * 64 + d4 + i;
        const float nrm = (val[i] - mu) * rs * lnxw[hj] + lnxb[hj];
        const float gp = gpre[eb + d4 + i];
        const float gv = gp / (1.f + expf(-gp));
        yv[i] = (short)f2bf(nrm * gv);
    }
    *(bf16x4*)(y + eb + d4) = yv;
}

extern "C" void kernel_launch(void* const* d_in, const int* in_sizes, int n_in,
                              void* d_out, int out_size, void* d_ws, size_t ws_size,
                              hipStream_t stream)
{
    const float* x     = (const float*)d_in[0];
    const float* state = (const float*)d_in[1];
    const float* ln1w  = (const float*)d_in[2];
    const float* ln1b  = (const float*)d_in[3];
    const float* maax  = (const float*)d_in[4];
    const float* w1    = (const float*)d_in[5];
    const float* w2    = (const float*)d_in[6];
    const float* maak  = (const float*)d_in[7];
    const float* maaw  = (const float*)d_in[8];
    const float* maav  = (const float*)d_in[9];
    const float* maar  = (const float*)d_in[10];
    const float* maag  = (const float*)d_in[11];
    const float* tdec  = (const float*)d_in[12];
    const float* dw1   = (const float*)d_in[13];
    const float* dw2   = (const float*)d_in[14];
    const float* fa    = (const float*)d_in[15];
    const float* wrec  = (const float*)d_in[16];
    const float* wkey  = (const float*)d_in[17];
    const float* wval  = (const float*)d_in[18];
    const float* wout  = (const float*)d_in[19];
    const float* wgate = (const float*)d_in[20];
    const float* lnxw  = (const float*)d_in[21];
    const float* lnxb  = (const float*)d_in[22];
    const int*   ip    = (const int*)d_in[23];

    char* ws = (char*)d_ws;
    const size_t MD = (size_t)M_ * D_;
    // lifetime-packed layout (78 MB budget)
    float* CS   = (float*)(ws);                          // [0,16)  rec phase
    float* RP   = (float*)(ws + ((size_t)16 << 20));     // [16,20)
    float* PC   = (float*)(ws + ((size_t)20 << 20));     // [20,20.25)
    float* pp1  = (float*)(ws);                          // [0,12) during gemm1g (CS/RP dead)
    float* xln  = (float*)(ws + ((size_t)40 << 20));     // [40,44)  dead after maa2
    float* sx   = (float*)(ws + ((size_t)44 << 20));     // [44,48)  dead after maa2
    u16*   xxxb = (u16*)  (ws + ((size_t)48 << 20));     // [48,50)  dead after wdot-maa1
    u16*   w1t  = (u16*)  (ws + ((size_t)50 << 20));     // [50,51)  dead after wdot-maa1
    u16*   dw1t = (u16*)  (ws + ((size_t)51 << 20));     // [51,52)  dead after wdot-decay1
    float* t5   = (float*)(ws + ((size_t)52 << 20));     // [52,53)  dead after maa2
    float* td   = (float*)(ws + ((size_t)53 << 20));     // [53,54)  dead after decay2
    u16*   x5   = (u16*)  (ws + ((size_t)54 << 20));     // [54,64)  dead after gemm4g
    float* wdec = (float*)(ws + ((size_t)64 << 20));     // [64,68)  dead after rec1
    float* kvK  = (float*)(ws + ((size_t)40 << 20));     // aliases xln  (dead)
    float* kvV  = (float*)(ws + ((size_t)44 << 20));     // aliases sx   (dead)
    float* kvR  = (float*)(ws + ((size_t)48 << 20));     // aliases xxxb/w1t/dw1t (dead)
    float* kvG  = (float*)(ws + ((size_t)68 << 20));     // [68,72)
    float* rwkv = (float*)(ws + ((size_t)72 << 20));     // [72,76)
    u16*   y    = (u16*)  (ws + ((size_t)76 << 20));     // [76,78)
    float* out  = (float*)d_out;

    hipLaunchKernelGGL(ln_kernel,     dim3(512),      dim3(256), 0, stream, x, ln1w, ln1b, xln);
    hipLaunchKernelGGL(shift_kernel,  dim3(1024),     dim3(256), 0, stream, xln, state, maax, ip, sx, xxxb);
    hipLaunchKernelGGL(txp_kernel,    dim3(64, 5),    dim3(256), 0, stream, w1, w1t, D_, 160);
    hipLaunchKernelGGL(txp_kernel,    dim3(64, 2),    dim3(256), 0, stream, dw1, dw1t, D_, 64);
    hipLaunchKernelGGL((wdot_kernel<true>), dim3(10240), dim3(512), 0, stream, xxxb, w1t, t5, 160);
    hipLaunchKernelGGL(maa2_kernel,   dim3(1024),     dim3(256), 0, stream, t5, w2, xln, sx, maak, maaw, maav, maar, maag, x5);
    hipLaunchKernelGGL((wdot_kernel<true>), dim3(4096), dim3(512), 0, stream, x5 + MD, dw1t, td, 64);
    hipLaunchKernelGGL(decay2_kernel, dim3(1024),     dim3(256), 0, stream, td, dw2, tdec, wdec);
    hipLaunchKernelGGL(gemm4g_kernel, dim3(32, 4, 4), dim3(512), 0, stream, x5, wkey, wval, wrec, wgate, kvK, kvV, kvR, kvG);
    hipLaunchKernelGGL(rec1_kernel,   dim3(B_ * H_ * NC_), dim3(512), 0, stream, kvR, kvK, wdec, kvV, fa, rwkv, CS, RP, PC);
    hipLaunchKernelGGL(rec2_kernel,   dim3(B_ * H_),  dim3(512), 0, stream, state, ip, CS, PC);
    hipLaunchKernelGGL(rec3gn_kernel, dim3(B_ * H_ * NC_), dim3(256), 0, stream, CS, RP, rwkv, kvG, lnxw, lnxb, y);
    hipLaunchKernelGGL(gemm1g_kernel, dim3(32, 4, 4), dim3(512), 0, stream, y, wout, out, pp1);
    hipLaunchKernelGGL(add3_kernel,   dim3(1024),     dim3(256), 0, stream, out, pp1);

    (void)in_sizes; (void)n_in; (void)out_size; (void)ws_size;
}